// Round 22
// baseline (402.635 us; speedup 1.0000x reference)
//
#include <hip/hip_runtime.h>
#include <hip/hip_bf16.h>
#include <cstdint>
#include <cstddef>

typedef unsigned short u16;
typedef __bf16 bhalf8 __attribute__((ext_vector_type(8)));
typedef float floatx4 __attribute__((ext_vector_type(4)));
typedef unsigned short u16x8 __attribute__((ext_vector_type(8)));

__device__ __forceinline__ float b2f(u16 u){
  union { uint32_t i; float f; } x; x.i = ((uint32_t)u) << 16; return x.f;
}
__device__ __forceinline__ u16 f2b(float f){
  uint32_t i = __float_as_uint(f);
  uint32_t r = (i + 0x7FFFu + ((i >> 16) & 1u)) >> 16;   // round-nearest-even
  return (u16)r;
}

// async global->LDS DMA, 16B per lane; LDS dest = wave-uniform base + lane*16
__device__ __forceinline__ void gload16(const u16* g, u16* l){
  __builtin_amdgcn_global_load_lds(
      (const __attribute__((address_space(1))) uint32_t*)g,
      (__attribute__((address_space(3))) uint32_t*)l, 16, 0, 0);
}

// ---- block-wide sum over 256 threads (4 waves) ----
__device__ __forceinline__ float block_sum256(float v, float* sh){
  #pragma unroll
  for (int o = 32; o > 0; o >>= 1) v += __shfl_down(v, o);
  __syncthreads();
  if ((threadIdx.x & 63u) == 0) sh[threadIdx.x >> 6] = v;
  __syncthreads();
  return sh[0] + sh[1] + sh[2] + sh[3];
}

// ---- wave-wide sum over 64 lanes ----
__device__ __forceinline__ float wave_sum(float v){
  #pragma unroll
  for (int o = 32; o > 0; o >>= 1) v += __shfl_xor(v, o);
  return v;
}

// ---- per-row LN stats of visual_feat (fp32), rearranged row order ----
__global__ __launch_bounds__(256) void stats_x_k(
    const float* __restrict__ vf, float2* __restrict__ st)
{
  __shared__ float sh[4];
  const int r  = blockIdx.x;
  const int nn = r & 255, bt = r >> 8;
  const float* in = vf + ((size_t)nn * 128 + bt) * 768;
  const int t = threadIdx.x;
  float v0 = in[t], v1 = in[t + 256], v2 = in[t + 512];
  float mean = block_sum256(v0 + v1 + v2, sh) * (1.0f / 768.0f);
  float d0 = v0 - mean, d1 = v1 - mean, d2 = v2 - mean;
  float var = block_sum256(d0*d0 + d1*d1 + d2*d2, sh) * (1.0f / 768.0f);
  if (t == 0) st[r] = make_float2(mean, rsqrtf(var + 1e-5f));
}

// ---- LN of visual_feat -> bf16 xm, rearranged rows; ONE WAVE PER ROW ----
__global__ __launch_bounds__(256) void ln_x_k(
    const float* __restrict__ vf, u16* __restrict__ xm,
    const float* __restrict__ g, const float* __restrict__ b)
{
  const int r  = blockIdx.x * 4 + (threadIdx.x >> 6);  // output row
  const int ln = threadIdx.x & 63;
  const int nn = r & 255, bt = r >> 8;
  const float* in = vf + ((size_t)nn * 128 + bt) * 768;
  float4 v[3];
  #pragma unroll
  for (int i = 0; i < 3; i++) v[i] = *(const float4*)(in + i * 256 + ln * 4);
  float s = 0.f;
  #pragma unroll
  for (int i = 0; i < 3; i++) s += v[i].x + v[i].y + v[i].z + v[i].w;
  const float mean = wave_sum(s) * (1.0f / 768.0f);
  float q = 0.f;
  #pragma unroll
  for (int i = 0; i < 3; i++){
    float dx = v[i].x - mean, dy = v[i].y - mean, dz = v[i].z - mean, dw = v[i].w - mean;
    q += dx*dx + dy*dy + dz*dz + dw*dw;
  }
  const float rs = rsqrtf(wave_sum(q) * (1.0f / 768.0f) + 1e-5f);
  #pragma unroll
  for (int i = 0; i < 3; i++){
    const int c = i * 256 + ln * 4;
    float4 gv = *(const float4*)(g + c);
    float4 bv = *(const float4*)(b + c);
    ushort4 o;
    o.x = f2b((v[i].x - mean) * rs * gv.x + bv.x);
    o.y = f2b((v[i].y - mean) * rs * gv.y + bv.y);
    o.z = f2b((v[i].z - mean) * rs * gv.z + bv.z);
    o.w = f2b((v[i].w - mean) * rs * gv.w + bv.w);
    *(ushort4*)(xm + (size_t)r * 768 + c) = o;
  }
}

// ---- double LayerNorm of latents (fp32 in) -> bf16 ----
__global__ __launch_bounds__(256) void ln_lat2_k(
    const float* __restrict__ lat, u16* __restrict__ ll,
    const float* __restrict__ g0, const float* __restrict__ b0,
    const float* __restrict__ g1, const float* __restrict__ b1)
{
  __shared__ float sh[4];
  const int r = blockIdx.x;
  const int t = threadIdx.x;
  const float* in = lat + (size_t)r * 768;
  float v[3];
  #pragma unroll
  for (int i = 0; i < 3; i++) v[i] = in[t + 256 * i];
  #pragma unroll
  for (int pass = 0; pass < 2; ++pass){
    float mean = block_sum256(v[0] + v[1] + v[2], sh) * (1.0f / 768.0f);
    float d0 = v[0] - mean, d1 = v[1] - mean, d2 = v[2] - mean;
    float var = block_sum256(d0*d0 + d1*d1 + d2*d2, sh) * (1.0f / 768.0f);
    float rs = rsqrtf(var + 1e-5f);
    const float* g = pass ? g1 : g0;
    const float* b = pass ? b1 : b0;
    #pragma unroll
    for (int i = 0; i < 3; i++){
      int c = t + 256 * i;
      v[i] = (v[i] - mean) * rs * g[c] + b[c];
    }
  }
  #pragma unroll
  for (int i = 0; i < 3; i++) ll[(size_t)r * 768 + t + 256 * i] = f2b(v[i]);
}

// ---- LN of fp32 ws rows -> bf16; ONE WAVE PER ROW (4 rows/block) ----
__global__ __launch_bounds__(256) void ln_f32_k(
    const float* __restrict__ y, u16* __restrict__ z,
    const float* __restrict__ g, const float* __restrict__ b)
{
  const int r  = blockIdx.x * 4 + (threadIdx.x >> 6);
  const int ln = threadIdx.x & 63;
  const float* in = y + (size_t)r * 768;
  float4 v[3];
  #pragma unroll
  for (int i = 0; i < 3; i++) v[i] = *(const float4*)(in + i * 256 + ln * 4);
  float s = 0.f;
  #pragma unroll
  for (int i = 0; i < 3; i++) s += v[i].x + v[i].y + v[i].z + v[i].w;
  const float mean = wave_sum(s) * (1.0f / 768.0f);
  float q = 0.f;
  #pragma unroll
  for (int i = 0; i < 3; i++){
    float dx = v[i].x - mean, dy = v[i].y - mean, dz = v[i].z - mean, dw = v[i].w - mean;
    q += dx*dx + dy*dy + dz*dz + dw*dw;
  }
  const float rs = rsqrtf(wave_sum(q) * (1.0f / 768.0f) + 1e-5f);
  #pragma unroll
  for (int i = 0; i < 3; i++){
    const int c = i * 256 + ln * 4;
    float4 gv = *(const float4*)(g + c);
    float4 bv = *(const float4*)(b + c);
    ushort4 o;
    o.x = f2b((v[i].x - mean) * rs * gv.x + bv.x);
    o.y = f2b((v[i].y - mean) * rs * gv.y + bv.y);
    o.z = f2b((v[i].z - mean) * rs * gv.z + bv.z);
    o.w = f2b((v[i].w - mean) * rs * gv.w + bv.w);
    *(ushort4*)(z + (size_t)r * 768 + c) = o;
  }
}

// ---- batched weight transpose + bf16 convert: up to 5 matrices per launch ----
__global__ __launch_bounds__(256) void transpB_k(
    const float* s0, u16* d0, int K0, int N0, int e0,
    const float* s1, u16* d1, int K1, int N1, int e1,
    const float* s2, u16* d2, int K2, int N2, int e2,
    const float* s3, u16* d3, int K3, int N3, int e3,
    const float* s4, u16* d4, int K4, int N4, int e4)
{
  __shared__ u16 sh[32][33];
  const int b = blockIdx.x;
  const float* src; u16* dst; int K, N, base;
  if      (b < e0){ src = s0; dst = d0; K = K0; N = N0; base = 0;  }
  else if (b < e1){ src = s1; dst = d1; K = K1; N = N1; base = e0; }
  else if (b < e2){ src = s2; dst = d2; K = K2; N = N2; base = e1; }
  else if (b < e3){ src = s3; dst = d3; K = K3; N = N3; base = e2; }
  else            { src = s4; dst = d4; K = K4; N = N4; base = e3; }
  const int lb = b - base;
  const int nb = N >> 5;
  const int bx = lb % nb, byy = lb / nb;
  const int tx = threadIdx.x & 31, ty = threadIdx.x >> 5;
  #pragma unroll
  for (int i = 0; i < 4; i++){
    int k = byy * 32 + ty + i * 8, n = bx * 32 + tx;
    sh[tx][ty + i * 8] = f2b(src[(size_t)k * N + n]);
  }
  __syncthreads();
  #pragma unroll
  for (int i = 0; i < 4; i++){
    int n = bx * 32 + ty + i * 8, k = byy * 32 + tx;
    dst[(size_t)n * K + k] = sh[ty + i * 8][tx];
  }
}

// ---- 128x256 MFMA GEMM (R19-proven): 8 waves x (64x64), 3-buffer rotation,
// ONE barrier per K-step, counted vmcnt(3); LDS-staged vectorized epilogues.
__global__ __launch_bounds__(512) void mgemmW_k(
    const u16* __restrict__ A, const u16* __restrict__ BT, void* __restrict__ C,
    int M, int N, int K,
    const float* __restrict__ bias, int act,
    const float* addsrc, int rowperm, int outbf16)
{
  __shared__ __align__(16) u16 smem[36864];      // 73,728 B
  u16 (*As)[32] = (u16 (*)[32])smem;             // [3*128][32]
  u16 (*Bs)[32] = (u16 (*)[32])(smem + 12288);   // [3*256][32]
  const int nb = N >> 8;
  const int swz = ((blockIdx.x & 7) * (gridDim.x >> 3)) + (blockIdx.x >> 3);
  const int bx = swz % nb, by = swz / nb;
  const int tid = threadIdx.x;
  const int wave = tid >> 6, lane = tid & 63;
  const int wr = (wave >> 2) * 64;        // M-half
  const int wc = (wave & 3) * 64;         // N-quarter
  const int l15 = lane & 15, l4 = lane >> 4;
  const int srow = lane >> 2, sseg = lane & 3;   // staging: 16 rows x 4 segs

  floatx4 acc[4][4];
  #pragma unroll
  for (int i = 0; i < 4; i++)
    #pragma unroll
    for (int j = 0; j < 4; j++) acc[i][j] = (floatx4){0.f, 0.f, 0.f, 0.f};

  auto stage = [&](int buf, int k0){
    gload16(A + (size_t)(by * 128 + wave * 16 + srow) * K + k0 + sseg * 8,
            &As[buf * 128 + wave * 16][0]);
    #pragma unroll
    for (int c = 0; c < 2; c++){
      gload16(BT + (size_t)(bx * 256 + wave * 32 + c * 16 + srow) * K + k0 + sseg * 8,
              &Bs[buf * 256 + wave * 32 + c * 16][0]);
    }
  };
  auto domfma = [&](int buf){
    bhalf8 af[4], bfv[4];
    #pragma unroll
    for (int i = 0; i < 4; i++){
      af[i]  = *(const bhalf8*)(&As[buf * 128 + wr + i * 16 + l15][l4 * 8]);
      bfv[i] = *(const bhalf8*)(&Bs[buf * 256 + wc + i * 16 + l15][l4 * 8]);
    }
    #pragma unroll
    for (int i = 0; i < 4; i++)
      #pragma unroll
      for (int j = 0; j < 4; j++)
        acc[i][j] = __builtin_amdgcn_mfma_f32_16x16x32_bf16(af[i], bfv[j], acc[i][j], 0, 0, 0);
  };

  stage(0, 0);
  const int nk = K >> 5;
  int cur = 0;
  for (int kt = 0; kt < nk; ++kt){
    if (kt + 1 < nk){
      const int nxt = (cur + 1 == 3) ? 0 : cur + 1;
      stage(nxt, (kt + 1) << 5);              // prefetch next K-tile
      asm volatile("s_waitcnt vmcnt(3)" ::: "memory");  // cur done; 3 in flight
    } else {
      asm volatile("s_waitcnt vmcnt(0)" ::: "memory");  // tail: drain
    }
    __builtin_amdgcn_s_barrier();
    __builtin_amdgcn_s_setprio(1);
    domfma(cur);
    __builtin_amdgcn_s_setprio(0);
    cur = (cur + 1 == 3) ? 0 : cur + 1;
  }

  const int gm0 = by * 128 + wr, gn0 = bx * 256 + wc;
  __syncthreads();                         // all waves done with staging LDS
  if (outbf16){
    u16* sc = smem + wave * 4608;          // per-wave [64][72] u16 scratch
    #pragma unroll
    for (int i = 0; i < 4; i++){
      #pragma unroll
      for (int j = 0; j < 4; j++){
        const int gn = gn0 + j * 16 + l15;
        #pragma unroll
        for (int r = 0; r < 4; r++){
          float v = acc[i][j][r];
          if (bias) v += bias[gn];
          if (act)  v = v * (1.0f / (1.0f + expf(-1.702f * v)));  // QuickGELU
          sc[(i * 16 + l4 * 4 + r) * 72 + j * 16 + l15] = f2b(v);
        }
      }
    }
    u16* Cp = (u16*)C;
    const int lr = lane >> 3, lcb = (lane & 7) * 8;
    #pragma unroll
    for (int p = 0; p < 8; p++){
      u16x8 v = *(const u16x8*)(sc + (p * 8 + lr) * 72 + lcb);
      *(u16x8*)(Cp + (size_t)(gm0 + p * 8 + lr) * N + gn0 + lcb) = v;
    }
  } else {
    float* scf = (float*)smem + wave * 2304;   // per-wave [32][72] f32 scratch
    const int rr = lane >> 4, cc = (lane & 15) * 4;
    #pragma unroll
    for (int h = 0; h < 2; h++){               // two 32-row half-tiles
      #pragma unroll
      for (int ii = 0; ii < 2; ii++){
        const int i = h * 2 + ii;
        #pragma unroll
        for (int j = 0; j < 4; j++){
          const int gn = gn0 + j * 16 + l15;
          #pragma unroll
          for (int r = 0; r < 4; r++){
            float v = acc[i][j][r];
            if (bias) v += bias[gn];
            if (act)  v = v * (1.0f / (1.0f + expf(-1.702f * v)));
            scf[(ii * 16 + l4 * 4 + r) * 72 + j * 16 + l15] = v;
          }
        }
      }
      #pragma unroll
      for (int it = 0; it < 8; it++){
        const int row32 = it * 4 + rr;
        float4 v = *(const float4*)(scf + row32 * 72 + cc);
        const int gm = gm0 + h * 32 + row32;
        const int orow = rowperm ? ((gm & 63) * 128 + (gm >> 6)) : gm;
        if (addsrc){
          float4 a = *(const float4*)(addsrc + (size_t)orow * N + gn0 + cc);
          v.x += a.x; v.y += a.y; v.z += a.z; v.w += a.w;
        }
        *(float4*)((float*)C + (size_t)orow * N + gn0 + cc) = v;
      }
    }
  }
}

// ---- 128x128 MFMA GEMM, AMODE-1 only (fp32 vf + fused LN fallback) ----
template<int AMODE>
__global__ __launch_bounds__(256) void mgemm_k(
    const void* __restrict__ A, const u16* __restrict__ BT, void* __restrict__ C,
    int M, int N, int K,
    const float* __restrict__ bias, int act,
    const float* addsrc, int rowperm, int outbf16,
    const float2* __restrict__ stx, const float* __restrict__ gam,
    const float* __restrict__ bet)
{
  __shared__ __align__(16) u16 As[2][128][32];
  __shared__ __align__(16) u16 Bs[2][128][32];
  const int nb = N >> 7;
  const int swz = ((blockIdx.x & 7) * (gridDim.x >> 3)) + (blockIdx.x >> 3);
  const int bx = swz % nb, by = swz / nb;
  const int tid  = threadIdx.x;
  const int wave = tid >> 6, lane = tid & 63;
  const int wr = (wave >> 1) * 64, wc = (wave & 1) * 64;
  const int l15 = lane & 15, l4 = lane >> 4;
  const int srow = lane >> 2, sseg = lane & 3;
  const int sr = tid >> 2, sq = (tid & 3) * 8;

  const float* Af  = (const float*)A;

  floatx4 acc[4][4];
  #pragma unroll
  for (int i = 0; i < 4; i++)
    #pragma unroll
    for (int j = 0; j < 4; j++) acc[i][j] = (floatx4){0.f, 0.f, 0.f, 0.f};

  auto domfma = [&](int buf){
    bhalf8 af[4], bfv[4];
    #pragma unroll
    for (int i = 0; i < 4; i++){
      af[i]  = *(const bhalf8*)(&As[buf][wr + i * 16 + l15][l4 * 8]);
      bfv[i] = *(const bhalf8*)(&Bs[buf][wc + i * 16 + l15][l4 * 8]);
    }
    #pragma unroll
    for (int i = 0; i < 4; i++)
      #pragma unroll
      for (int j = 0; j < 4; j++)
        acc[i][j] = __builtin_amdgcn_mfma_f32_16x16x32_bf16(af[i], bfv[j], acc[i][j], 0, 0, 0);
  };

  {
    int   asrc[2]; float mn[2], rs[2];
    #pragma unroll
    for (int p = 0; p < 2; p++){
      int gm = by * 128 + sr + p * 64;
      asrc[p] = (gm & 255) * 128 + (gm >> 8);
      float2 s = stx[gm]; mn[p] = s.x; rs[p] = s.y;
    }
    for (int k0 = 0; k0 < K; k0 += 32){
      #pragma unroll
      for (int p = 0; p < 2; p++){
        const int r = sr + p * 64;
        const float* ap = Af + (size_t)asrc[p] * K + k0 + sq;
        float4 f0 = *(const float4*)ap, f1 = *(const float4*)(ap + 4);
        float4 g0 = *(const float4*)(gam + k0 + sq), g1 = *(const float4*)(gam + k0 + sq + 4);
        float4 e0 = *(const float4*)(bet + k0 + sq), e1 = *(const float4*)(bet + k0 + sq + 4);
        u16x8 v;
        v[0] = f2b((f0.x - mn[p]) * rs[p] * g0.x + e0.x);
        v[1] = f2b((f0.y - mn[p]) * rs[p] * g0.y + e0.y);
        v[2] = f2b((f0.z - mn[p]) * rs[p] * g0.z + e0.z);
        v[3] = f2b((f0.w - mn[p]) * rs[p] * g0.w + e0.w);
        v[4] = f2b((f1.x - mn[p]) * rs[p] * g1.x + e1.x);
        v[5] = f2b((f1.y - mn[p]) * rs[p] * g1.y + e1.y);
        v[6] = f2b((f1.z - mn[p]) * rs[p] * g1.z + e1.z);
        v[7] = f2b((f1.w - mn[p]) * rs[p] * g1.w + e1.w);
        *(u16x8*)(&As[0][r][sq]) = v;
      }
      #pragma unroll
      for (int c = 0; c < 2; c++){
        const int ch = wave * 2 + c;
        gload16(BT + (size_t)(bx * 128 + ch * 16 + srow) * K + k0 + sseg * 8,
                &Bs[0][ch * 16][0]);
      }
      __syncthreads();
      domfma(0);
      __syncthreads();
    }
  }

  const int gm0 = by * 128 + wr, gn0 = bx * 128 + wc;
  #pragma unroll
  for (int i = 0; i < 4; i++){
    #pragma unroll
    for (int r = 0; r < 4; r++){
      int gm = gm0 + i * 16 + l4 * 4 + r;
      int orow = rowperm ? ((gm & 63) * 128 + (gm >> 6)) : gm;
      #pragma unroll
      for (int j = 0; j < 4; j++){
        int gn = gn0 + j * 16 + l15;
        float v = acc[i][j][r];
        if (bias) v += bias[gn];
        if (act)  v = v * (1.0f / (1.0f + expf(-1.702f * v)));
        if (addsrc) v += addsrc[(size_t)orow * N + gn];
        if (outbf16) ((u16*)C)[(size_t)orow * N + gn] = f2b(v);
        else         ((float*)C)[(size_t)orow * N + gn] = v;
      }
    }
  }
}

// ---- MFMA Perceiver attention: block=(bt,head), 4 waves x 16 q-rows ----
// q/kvll in combined buffer qkv512 [512][1536]: q cols [0,512),
// K at 512+h*64, V at 1024+h*64. Output staged via Ks (dead after pass 1)
// -> u16x8 vectorized stores (128B segments).
__global__ __launch_bounds__(256) void pattn_k(
    const u16* __restrict__ qc, const u16* __restrict__ kvx,
    u16* __restrict__ o)
{
  __shared__ __align__(16) u16 Ks[64][72];
  __shared__ __align__(16) u16 Vs[64][72];
  __shared__ __align__(16) u16 Ps[64][72];
  const int blk = blockIdx.x;            // bt*8 + h
  const int hh = blk & 7, bt = blk >> 3;
  const int tt = bt & 7;
  const int tid = threadIdx.x;
  const int wv = tid >> 6, ln = tid & 63;
  const int l15 = ln & 15, lg = ln >> 4;
  const int i0 = wv * 16;
  const int sj = tid >> 2, sc = (tid & 3) * 16;

  bhalf8 qf[2];
  {
    const u16* qp = qc + ((size_t)(tt * 64 + i0 + l15)) * 1536 + hh * 64 + lg * 8;
    qf[0] = *(const bhalf8*)(qp);
    qf[1] = *(const bhalf8*)(qp + 32);
  }

  floatx4 sacc[20];
  #pragma unroll
  for (int t = 0; t < 20; t++) sacc[t] = (floatx4){0.f,0.f,0.f,0.f};

  for (int ch = 0; ch < 5; ++ch){
    const u16* src = (ch < 4)
        ? (kvx + ((size_t)(bt * 256 + ch * 64 + sj)) * 1024 + hh * 64 + sc)
        : (qc  + ((size_t)(tt * 64 + sj)) * 1536 + 512 + hh * 64 + sc);
    u16x8 k0 = *(const u16x8*)(src);
    u16x8 k1 = *(const u16x8*)(src + 8);
    __syncthreads();
    *(u16x8*)(&Ks[sj][sc])     = k0;
    *(u16x8*)(&Ks[sj][sc + 8]) = k1;
    __syncthreads();
    #pragma unroll
    for (int jt = 0; jt < 4; jt++){
      bhalf8 kf0 = *(const bhalf8*)(&Ks[jt*16 + l15][lg*8]);
      bhalf8 kf1 = *(const bhalf8*)(&Ks[jt*16 + l15][32 + lg*8]);
      sacc[ch*4+jt] = __builtin_amdgcn_mfma_f32_16x16x32_bf16(qf[0], kf0, sacc[ch*4+jt], 0,0,0);
      sacc[ch*4+jt] = __builtin_amdgcn_mfma_f32_16x16x32_bf16(qf[1], kf1, sacc[ch*4+jt], 0,0,0);
    }
  }

  float inv_l[4];
  float mx[4];
  #pragma unroll
  for (int r = 0; r < 4; r++){
    float m = -1e30f;
    #pragma unroll
    for (int t = 0; t < 20; t++) m = fmaxf(m, sacc[t][r]);
    m = fmaxf(m, __shfl_xor(m, 1));
    m = fmaxf(m, __shfl_xor(m, 2));
    m = fmaxf(m, __shfl_xor(m, 4));
    m = fmaxf(m, __shfl_xor(m, 8));
    mx[r] = m;
  }
  #pragma unroll
  for (int r = 0; r < 4; r++){
    float s = 0.f;
    #pragma unroll
    for (int t = 0; t < 20; t++){
      float p = expf(0.125f * (sacc[t][r] - mx[r]));
      sacc[t][r] = p;
      s += p;
    }
    s += __shfl_xor(s, 1); s += __shfl_xor(s, 2);
    s += __shfl_xor(s, 4); s += __shfl_xor(s, 8);
    inv_l[r] = 1.0f / s;
  }

  floatx4 oacc[4];
  #pragma unroll
  for (int dt = 0; dt < 4; dt++) oacc[dt] = (floatx4){0.f,0.f,0.f,0.f};
  for (int ch = 0; ch < 5; ++ch){
    const u16* src = (ch < 4)
        ? (kvx + ((size_t)(bt * 256 + ch * 64 + sj)) * 1024 + 512 + hh * 64 + sc)
        : (qc  + ((size_t)(tt * 64 + sj)) * 1536 + 1024 + hh * 64 + sc);
    u16x8 v0 = *(const u16x8*)(src);
    u16x8 v1 = *(const u16x8*)(src + 8);
    __syncthreads();
    #pragma unroll
    for (int e = 0; e < 8; e++) Vs[sc + e][sj]     = v0[e];
    #pragma unroll
    for (int e = 0; e < 8; e++) Vs[sc + 8 + e][sj] = v1[e];
    #pragma unroll
    for (int jt = 0; jt < 4; jt++){
      #pragma unroll
      for (int r = 0; r < 4; r++)
        Ps[i0 + 4*lg + r][jt*16 + l15] = f2b(sacc[ch*4+jt][r]);
    }
    __syncthreads();
    #pragma unroll
    for (int kk = 0; kk < 2; kk++){
      bhalf8 pf = *(const bhalf8*)(&Ps[i0 + l15][kk*32 + lg*8]);
      #pragma unroll
      for (int dt = 0; dt < 4; dt++){
        bhalf8 vfr = *(const bhalf8*)(&Vs[dt*16 + l15][kk*32 + lg*8]);
        oacc[dt] = __builtin_amdgcn_mfma_f32_16x16x32_bf16(pf, vfr, oacc[dt], 0,0,0);
      }
    }
  }

  // ---- vectorized epilogue: stage wave's 16x64 tile into Ks rows i0..i0+15
  // (dead after pass 1; wave-private rows, DS ops are wave-in-order) ----
  #pragma unroll
  for (int dt = 0; dt < 4; dt++)
    #pragma unroll
    for (int r = 0; r < 4; r++)
      Ks[i0 + 4*lg + r][dt*16 + l15] = f2b(oacc[dt][r] * inv_l[r]);
  const int lr = ln >> 3, lcb = (ln & 7) * 8;
  #pragma unroll
  for (int p = 0; p < 2; p++){
    const int row = i0 + p * 8 + lr;
    u16x8 v = *(const u16x8*)(&Ks[row][lcb]);
    *(u16x8*)(o + ((size_t)(bt * 64 + row)) * 512 + hh * 64 + lcb) = v;
  }
}

// ---- MFMA self-attention: block=(bt,head), 4 waves x 16 q-rows, 64 keys ----
__global__ __launch_bounds__(256) void sattn_k(
    const u16* __restrict__ qkv, u16* __restrict__ o2)
{
  __shared__ __align__(16) u16 Ks[64][72];
  __shared__ __align__(16) u16 Vs[64][72];
  __shared__ __align__(16) u16 Ps[64][72];
  const int blk = blockIdx.x;
  const int hh = blk % 12, bt = blk / 12;
  const int tid = threadIdx.x;
  const int wv = tid >> 6, ln = tid & 63;
  const int l15 = ln & 15, lg = ln >> 4;
  const int i0 = wv * 16;
  const int sj = tid >> 2, sc = (tid & 3) * 16;

  const u16* kp = qkv + ((size_t)sj * 128 + bt) * 2304 + 768 + hh * 64 + sc;
  u16x8 k0 = *(const u16x8*)(kp);
  u16x8 k1 = *(const u16x8*)(kp + 8);
  u16x8 v0 = *(const u16x8*)(kp + 768);
  u16x8 v1 = *(const u16x8*)(kp + 776);
  *(u16x8*)(&Ks[sj][sc])     = k0;
  *(u16x8*)(&Ks[sj][sc + 8]) = k1;
  #pragma unroll
  for (int e = 0; e < 8; e++) Vs[sc + e][sj]     = v0[e];
  #pragma unroll
  for (int e = 0; e < 8; e++) Vs[sc + 8 + e][sj] = v1[e];

  bhalf8 qf[2];
  {
    const u16* qp = qkv + ((size_t)(i0 + l15) * 128 + bt) * 2304 + hh * 64 + lg * 8;
    qf[0] = *(const bhalf8*)(qp);
    qf[1] = *(const bhalf8*)(qp + 32);
  }
  __syncthreads();

  floatx4 sacc[4];
  #pragma unroll
  for (int t = 0; t < 4; t++) sacc[t] = (floatx4){0.f,0.f,0.f,0.f};
  #pragma unroll
  for (int jt = 0; jt < 4; jt++){
    bhalf8 kf0 = *(const bhalf8*)(&Ks[jt*16 + l15][lg*8]);
    bhalf8 kf1 = *(const bhalf8*)(&Ks[jt*16 + l15][32 + lg*8]);
    sacc[jt] = __builtin_amdgcn_mfma_f32_16x16x32_bf16(qf[0], kf0, sacc[jt], 0,0,0);
    sacc[jt] = __builtin_amdgcn_mfma_f32_16x16x32_bf16(qf[1], kf1, sacc[jt], 0,0,0);
  }

  float inv_l[4];
  #pragma unroll
  for (int r = 0; r < 4; r++){
    float m = -1e30f;
    #pragma unroll
    for (int t = 0; t < 4; t++) m = fmaxf(m, sacc[t][r]);
    m = fmaxf(m, __shfl_xor(m, 1));
    m = fmaxf(m, __shfl_xor(m, 2));
    m = fmaxf(m, __shfl_xor(m, 4));
    m = fmaxf(m, __shfl_xor(m, 8));
    float s = 0.f;
    #pragma unroll
    for (int t = 0; t < 4; t++){
      float p = expf(0.125f * (sacc[t][r] - m));
      sacc[t][r] = p;
      s += p;
    }
    s += __shfl_xor(s, 1); s += __shfl_xor(s, 2);
    s += __shfl_xor(s, 4); s += __shfl_xor(s, 8);
    inv_l[r] = 1.0f / s;
  }

  #pragma unroll
  for (int jt = 0; jt < 4; jt++){
    #pragma unroll
    for (int r = 0; r < 4; r++)
      Ps[i0 + 4*lg + r][jt*16 + l15] = f2b(sacc[jt][r]);
  }
  __syncthreads();

  floatx4 oacc[4];
  #pragma unroll
  for (int dt = 0; dt < 4; dt++) oacc[dt] = (floatx4){0.f,0.f,0.f,0.f};
  #pragma unroll
  for (int kk = 0; kk < 2; kk++){
    bhalf8 pf = *(const bhalf8*)(&Ps[i0 + l15][kk*32 + lg*8]);
    #pragma unroll
    for (int dt = 0; dt < 4; dt++){
      bhalf8 vfr = *(const bhalf8*)(&Vs[dt*16 + l15][kk*32 + lg*8]);
      oacc[dt] = __builtin_amdgcn_mfma_f32_16x16x32_bf16(pf, vfr, oacc[dt], 0,0,0);
    }
  }

  // ---- vectorized epilogue via Ks scratch (dead after QK^T; wave-private) ----
  #pragma unroll
  for (int dt = 0; dt < 4; dt++)
    #pragma unroll
    for (int r = 0; r < 4; r++)
      Ks[i0 + 4*lg + r][dt*16 + l15] = f2b(oacc[dt][r] * inv_l[r]);
  const int lr = ln >> 3, lcb = (ln & 7) * 8;
  #pragma unroll
  for (int p = 0; p < 2; p++){
    const int row = i0 + p * 8 + lr;
    u16x8 v = *(const u16x8*)(&Ks[row][lcb]);
    *(u16x8*)(o2 + ((size_t)(row * 128 + bt)) * 768 + hh * 64 + lcb) = v;
  }
}

extern "C" void kernel_launch(void* const* d_in, const int* in_sizes, int n_in,
                              void* d_out, int out_size, void* d_ws, size_t ws_size,
                              hipStream_t stream)
{
  const float* vf   = (const float*)d_in[0];
  const float* lat  = (const float*)d_in[1];
  const float* nl0g = (const float*)d_in[2];
  const float* nl0b = (const float*)d_in[3];
  const float* pmg  = (const float*)d_in[4];
  const float* pmb  = (const float*)d_in[5];
  const float* plg  = (const float*)d_in[6];
  const float* plb  = (const float*)d_in[7];
  const float* Wq   = (const float*)d_in[8];
  const float* Wkv  = (const float*)d_in[9];
  const float* Wo   = (const float*)d_in[10];
  const float* ln1g = (const float*)d_in[11];
  const float* ln1b = (const float*)d_in[12];
  const float* Wqkv = (const float*)d_in[13];
  const float* bqkv = (const float*)d_in[14];
  const float* Wout = (const float*)d_in[15];
  const float* bout = (const float*)d_in[16];
  const float* ln2g = (const float*)d_in[17];
  const float* ln2b = (const float*)d_in[18];
  const float* Wfc  = (const float*)d_in[19];
  const float* bfc  = (const float*)d_in[20];
  const float* Wpr  = (const float*)d_in[21];
  const float* bpr  = (const float*)d_in[22];

  // ---- ws layout: base high-water 104,857,600 B; optional xm at 117.4M ----
  char* ws = (char*)d_ws;
  u16*    kvx    = (u16*)(ws + 0);          // 67,108,864 (dead after pattn)
  u16*    qkvb   = (u16*)(ws + 0);          // 37,748,736 (dead after sattn)
  u16*    o2b    = (u16*)(ws + 37748736);   // 12,582,912 (dead after Wout gemm)
  u16*    hb     = (u16*)(ws + 0);          // 50,331,648
  u16*    WoT    = (u16*)(ws + 50331648);
  u16*    WqkvT  = (u16*)(ws + 51118080);
  u16*    WoutT  = (u16*)(ws + 54657024);
  u16*    WfcT   = (u16*)(ws + 55836672);
  u16*    WprT   = (u16*)(ws + 60555264);   // ends 65,273,856
  u16*    WqT    = (u16*)(ws + 67108864);   // [512][768] then WkvT contiguous
  u16*    WkvT   = (u16*)(ws + 67895296);   // ends 69,468,160
  float*  yb     = (float*)(ws + 67108864); // written after WqT/WkvT dead
  u16*    llb    = (u16*)(ws + 92274688);
  u16*    qkv512 = (u16*)(ws + 93323264);   // [512][1536] bf16 (q|K|V)
  u16*    ob     = (u16*)(ws + 95420416);   // ends 103,809,024
  u16*    zb     = (u16*)(ws + 92274688);   // overlays llb..ob when dead
  u16*    xm     = (u16*)(ws + 117440512);  // 50,331,648, ends 167,772,160
  float2* stx    = (float2*)(ws + 93061120);
  const bool use_xm = (ws_size >= 167772160ull);

  const float* nof = nullptr;
  const float2* nos = nullptr;

  // early transposes: Wq (384 blks) + Wkv (768 blks) in ONE launch
  hipLaunchKernelGGL(transpB_k, dim3(1152), dim3(256), 0, stream,
                     Wq,  WqT,  768, 512,  384,
                     Wkv, WkvT, 768, 1024, 1152,
                     Wkv, WkvT, 768, 1024, 1152,
                     Wkv, WkvT, 768, 1024, 1152,
                     Wkv, WkvT, 768, 1024, 1152);
  hipLaunchKernelGGL(ln_lat2_k, dim3(512), dim3(256), 0, stream,
                     lat, llb, nl0g, nl0b, plg, plb);
  // q|kv_ll = ll @ [Wq|Wkv]: grid 4x6 = 24 blocks
  hipLaunchKernelGGL(mgemmW_k, dim3(24), dim3(512), 0, stream,
                     llb, WqT, (void*)qkv512, 512, 1536, 768, nof, 0, nof, 0, 1);
  if (use_xm){
    hipLaunchKernelGGL(ln_x_k, dim3(8192), dim3(256), 0, stream, vf, xm, pmg, pmb);
    // kv_x: 256x4 = 1024 blocks
    hipLaunchKernelGGL(mgemmW_k, dim3(1024), dim3(512), 0, stream,
                       xm, WkvT, (void*)kvx, 32768, 1024, 768, nof, 0, nof, 0, 1);
  } else {
    hipLaunchKernelGGL(stats_x_k, dim3(32768), dim3(256), 0, stream, vf, stx);
    hipLaunchKernelGGL(mgemm_k<1>, dim3(2048), dim3(256), 0, stream,
                       (const void*)vf, WkvT, (void*)kvx, 32768, 1024, 768,
                       nof, 0, nof, 0, 1, stx, pmg, pmb);
  }
  hipLaunchKernelGGL(pattn_k, dim3(1024), dim3(256), 0, stream, qkv512, kvx, ob);
  // late transposes in ONE launch
  hipLaunchKernelGGL(transpB_k, dim3(7296), dim3(256), 0, stream,
                     Wo,   WoT,   512,  768,  384,
                     Wqkv, WqkvT, 768,  2304, 2112,
                     Wout, WoutT, 768,  768,  2688,
                     Wfc,  WfcT,  768,  3072, 4992,
                     Wpr,  WprT,  3072, 768,  7296);
  // y = rearrange(ob @ Wo): 192 blocks (f32 out, rowperm)
  hipLaunchKernelGGL(mgemmW_k, dim3(192), dim3(512), 0, stream,
                     ob, WoT, (void*)yb, 8192, 768, 512, nof, 0, nof, 1, 0);
  hipLaunchKernelGGL(ln_f32_k, dim3(2048), dim3(256), 0, stream, yb, zb, ln1g, ln1b);
  // qkv: 576 blocks
  hipLaunchKernelGGL(mgemmW_k, dim3(576), dim3(512), 0, stream,
                     zb, WqkvT, (void*)qkvb, 8192, 2304, 768, bqkv, 0, nof, 0, 1);
  hipLaunchKernelGGL(sattn_k, dim3(1536), dim3(256), 0, stream, qkvb, o2b);
  // y += o2 @ Wout: 192 (f32 out, addsrc)
  hipLaunchKernelGGL(mgemmW_k, dim3(192), dim3(512), 0, stream,
                     o2b, WoutT, (void*)yb, 8192, 768, 768, bout, 0, yb, 0, 0);
  hipLaunchKernelGGL(ln_f32_k, dim3(2048), dim3(256), 0, stream, yb, zb, ln2g, ln2b);
  // h = QuickGELU(z2 @ fc): 768 blocks
  hipLaunchKernelGGL(mgemmW_k, dim3(768), dim3(512), 0, stream,
                     zb, WfcT, (void*)hb, 8192, 3072, 768, bfc, 1, nof, 0, 1);
  // out = y + h @ proj: 192 (K=3072, f32 out, addsrc)
  hipLaunchKernelGGL(mgemmW_k, dim3(192), dim3(512), 0, stream,
                     hb, WprT, d_out, 8192, 768, 3072, bpr, 0, yb, 0, 0);
}

// Round 23
// 391.909 us; speedup vs baseline: 1.0274x; 1.0274x over previous
//
#include <hip/hip_runtime.h>
#include <hip/hip_bf16.h>
#include <cstdint>
#include <cstddef>

typedef unsigned short u16;
typedef __bf16 bhalf8 __attribute__((ext_vector_type(8)));
typedef float floatx4 __attribute__((ext_vector_type(4)));
typedef unsigned short u16x8 __attribute__((ext_vector_type(8)));

__device__ __forceinline__ float b2f(u16 u){
  union { uint32_t i; float f; } x; x.i = ((uint32_t)u) << 16; return x.f;
}
__device__ __forceinline__ u16 f2b(float f){
  uint32_t i = __float_as_uint(f);
  uint32_t r = (i + 0x7FFFu + ((i >> 16) & 1u)) >> 16;   // round-nearest-even
  return (u16)r;
}

// async global->LDS DMA, 16B per lane; LDS dest = wave-uniform base + lane*16
__device__ __forceinline__ void gload16(const u16* g, u16* l){
  __builtin_amdgcn_global_load_lds(
      (const __attribute__((address_space(1))) uint32_t*)g,
      (__attribute__((address_space(3))) uint32_t*)l, 16, 0, 0);
}

// ---- block-wide sum over 256 threads (4 waves) ----
__device__ __forceinline__ float block_sum256(float v, float* sh){
  #pragma unroll
  for (int o = 32; o > 0; o >>= 1) v += __shfl_down(v, o);
  __syncthreads();
  if ((threadIdx.x & 63u) == 0) sh[threadIdx.x >> 6] = v;
  __syncthreads();
  return sh[0] + sh[1] + sh[2] + sh[3];
}

// ---- wave-wide sum over 64 lanes ----
__device__ __forceinline__ float wave_sum(float v){
  #pragma unroll
  for (int o = 32; o > 0; o >>= 1) v += __shfl_xor(v, o);
  return v;
}

// ---- per-row LN stats of visual_feat (fp32), rearranged row order ----
__global__ __launch_bounds__(256) void stats_x_k(
    const float* __restrict__ vf, float2* __restrict__ st)
{
  __shared__ float sh[4];
  const int r  = blockIdx.x;
  const int nn = r & 255, bt = r >> 8;
  const float* in = vf + ((size_t)nn * 128 + bt) * 768;
  const int t = threadIdx.x;
  float v0 = in[t], v1 = in[t + 256], v2 = in[t + 512];
  float mean = block_sum256(v0 + v1 + v2, sh) * (1.0f / 768.0f);
  float d0 = v0 - mean, d1 = v1 - mean, d2 = v2 - mean;
  float var = block_sum256(d0*d0 + d1*d1 + d2*d2, sh) * (1.0f / 768.0f);
  if (t == 0) st[r] = make_float2(mean, rsqrtf(var + 1e-5f));
}

// ---- LN of visual_feat -> bf16 xm, rearranged rows; ONE WAVE PER ROW ----
__global__ __launch_bounds__(256) void ln_x_k(
    const float* __restrict__ vf, u16* __restrict__ xm,
    const float* __restrict__ g, const float* __restrict__ b)
{
  const int r  = blockIdx.x * 4 + (threadIdx.x >> 6);  // output row
  const int ln = threadIdx.x & 63;
  const int nn = r & 255, bt = r >> 8;
  const float* in = vf + ((size_t)nn * 128 + bt) * 768;
  float4 v[3];
  #pragma unroll
  for (int i = 0; i < 3; i++) v[i] = *(const float4*)(in + i * 256 + ln * 4);
  float s = 0.f;
  #pragma unroll
  for (int i = 0; i < 3; i++) s += v[i].x + v[i].y + v[i].z + v[i].w;
  const float mean = wave_sum(s) * (1.0f / 768.0f);
  float q = 0.f;
  #pragma unroll
  for (int i = 0; i < 3; i++){
    float dx = v[i].x - mean, dy = v[i].y - mean, dz = v[i].z - mean, dw = v[i].w - mean;
    q += dx*dx + dy*dy + dz*dz + dw*dw;
  }
  const float rs = rsqrtf(wave_sum(q) * (1.0f / 768.0f) + 1e-5f);
  #pragma unroll
  for (int i = 0; i < 3; i++){
    const int c = i * 256 + ln * 4;
    float4 gv = *(const float4*)(g + c);
    float4 bv = *(const float4*)(b + c);
    ushort4 o;
    o.x = f2b((v[i].x - mean) * rs * gv.x + bv.x);
    o.y = f2b((v[i].y - mean) * rs * gv.y + bv.y);
    o.z = f2b((v[i].z - mean) * rs * gv.z + bv.z);
    o.w = f2b((v[i].w - mean) * rs * gv.w + bv.w);
    *(ushort4*)(xm + (size_t)r * 768 + c) = o;
  }
}

// ---- double LayerNorm of latents (fp32 in) -> bf16 ----
__global__ __launch_bounds__(256) void ln_lat2_k(
    const float* __restrict__ lat, u16* __restrict__ ll,
    const float* __restrict__ g0, const float* __restrict__ b0,
    const float* __restrict__ g1, const float* __restrict__ b1)
{
  __shared__ float sh[4];
  const int r = blockIdx.x;
  const int t = threadIdx.x;
  const float* in = lat + (size_t)r * 768;
  float v[3];
  #pragma unroll
  for (int i = 0; i < 3; i++) v[i] = in[t + 256 * i];
  #pragma unroll
  for (int pass = 0; pass < 2; ++pass){
    float mean = block_sum256(v[0] + v[1] + v[2], sh) * (1.0f / 768.0f);
    float d0 = v[0] - mean, d1 = v[1] - mean, d2 = v[2] - mean;
    float var = block_sum256(d0*d0 + d1*d1 + d2*d2, sh) * (1.0f / 768.0f);
    float rs = rsqrtf(var + 1e-5f);
    const float* g = pass ? g1 : g0;
    const float* b = pass ? b1 : b0;
    #pragma unroll
    for (int i = 0; i < 3; i++){
      int c = t + 256 * i;
      v[i] = (v[i] - mean) * rs * g[c] + b[c];
    }
  }
  #pragma unroll
  for (int i = 0; i < 3; i++) ll[(size_t)r * 768 + t + 256 * i] = f2b(v[i]);
}

// ---- LN of fp32 ws rows -> bf16; ONE WAVE PER ROW (4 rows/block) ----
__global__ __launch_bounds__(256) void ln_f32_k(
    const float* __restrict__ y, u16* __restrict__ z,
    const float* __restrict__ g, const float* __restrict__ b)
{
  const int r  = blockIdx.x * 4 + (threadIdx.x >> 6);
  const int ln = threadIdx.x & 63;
  const float* in = y + (size_t)r * 768;
  float4 v[3];
  #pragma unroll
  for (int i = 0; i < 3; i++) v[i] = *(const float4*)(in + i * 256 + ln * 4);
  float s = 0.f;
  #pragma unroll
  for (int i = 0; i < 3; i++) s += v[i].x + v[i].y + v[i].z + v[i].w;
  const float mean = wave_sum(s) * (1.0f / 768.0f);
  float q = 0.f;
  #pragma unroll
  for (int i = 0; i < 3; i++){
    float dx = v[i].x - mean, dy = v[i].y - mean, dz = v[i].z - mean, dw = v[i].w - mean;
    q += dx*dx + dy*dy + dz*dz + dw*dw;
  }
  const float rs = rsqrtf(wave_sum(q) * (1.0f / 768.0f) + 1e-5f);
  #pragma unroll
  for (int i = 0; i < 3; i++){
    const int c = i * 256 + ln * 4;
    float4 gv = *(const float4*)(g + c);
    float4 bv = *(const float4*)(b + c);
    ushort4 o;
    o.x = f2b((v[i].x - mean) * rs * gv.x + bv.x);
    o.y = f2b((v[i].y - mean) * rs * gv.y + bv.y);
    o.z = f2b((v[i].z - mean) * rs * gv.z + bv.z);
    o.w = f2b((v[i].w - mean) * rs * gv.w + bv.w);
    *(ushort4*)(z + (size_t)r * 768 + c) = o;
  }
}

// ---- batched weight transpose + bf16 convert: up to 5 matrices per launch ----
__global__ __launch_bounds__(256) void transpB_k(
    const float* s0, u16* d0, int K0, int N0, int e0,
    const float* s1, u16* d1, int K1, int N1, int e1,
    const float* s2, u16* d2, int K2, int N2, int e2,
    const float* s3, u16* d3, int K3, int N3, int e3,
    const float* s4, u16* d4, int K4, int N4, int e4)
{
  __shared__ u16 sh[32][33];
  const int b = blockIdx.x;
  const float* src; u16* dst; int K, N, base;
  if      (b < e0){ src = s0; dst = d0; K = K0; N = N0; base = 0;  }
  else if (b < e1){ src = s1; dst = d1; K = K1; N = N1; base = e0; }
  else if (b < e2){ src = s2; dst = d2; K = K2; N = N2; base = e1; }
  else if (b < e3){ src = s3; dst = d3; K = K3; N = N3; base = e2; }
  else            { src = s4; dst = d4; K = K4; N = N4; base = e3; }
  const int lb = b - base;
  const int nb = N >> 5;
  const int bx = lb % nb, byy = lb / nb;
  const int tx = threadIdx.x & 31, ty = threadIdx.x >> 5;
  #pragma unroll
  for (int i = 0; i < 4; i++){
    int k = byy * 32 + ty + i * 8, n = bx * 32 + tx;
    sh[tx][ty + i * 8] = f2b(src[(size_t)k * N + n]);
  }
  __syncthreads();
  #pragma unroll
  for (int i = 0; i < 4; i++){
    int n = bx * 32 + ty + i * 8, k = byy * 32 + tx;
    dst[(size_t)n * K + k] = sh[ty + i * 8][tx];
  }
}

// ---- 128x256 MFMA GEMM (R19-proven): 8 waves x (64x64), 3-buffer rotation,
// ONE barrier per K-step, counted vmcnt(3); LDS-staged vectorized epilogues.
// QuickGELU uses fast __expf (native exp) — libm expf was 44% VALUBusy on fc.
__global__ __launch_bounds__(512) void mgemmW_k(
    const u16* __restrict__ A, const u16* __restrict__ BT, void* __restrict__ C,
    int M, int N, int K,
    const float* __restrict__ bias, int act,
    const float* addsrc, int rowperm, int outbf16)
{
  __shared__ __align__(16) u16 smem[36864];      // 73,728 B
  u16 (*As)[32] = (u16 (*)[32])smem;             // [3*128][32]
  u16 (*Bs)[32] = (u16 (*)[32])(smem + 12288);   // [3*256][32]
  const int nb = N >> 8;
  const int swz = ((blockIdx.x & 7) * (gridDim.x >> 3)) + (blockIdx.x >> 3);
  const int bx = swz % nb, by = swz / nb;
  const int tid = threadIdx.x;
  const int wave = tid >> 6, lane = tid & 63;
  const int wr = (wave >> 2) * 64;        // M-half
  const int wc = (wave & 3) * 64;         // N-quarter
  const int l15 = lane & 15, l4 = lane >> 4;
  const int srow = lane >> 2, sseg = lane & 3;   // staging: 16 rows x 4 segs

  floatx4 acc[4][4];
  #pragma unroll
  for (int i = 0; i < 4; i++)
    #pragma unroll
    for (int j = 0; j < 4; j++) acc[i][j] = (floatx4){0.f, 0.f, 0.f, 0.f};

  auto stage = [&](int buf, int k0){
    gload16(A + (size_t)(by * 128 + wave * 16 + srow) * K + k0 + sseg * 8,
            &As[buf * 128 + wave * 16][0]);
    #pragma unroll
    for (int c = 0; c < 2; c++){
      gload16(BT + (size_t)(bx * 256 + wave * 32 + c * 16 + srow) * K + k0 + sseg * 8,
              &Bs[buf * 256 + wave * 32 + c * 16][0]);
    }
  };
  auto domfma = [&](int buf){
    bhalf8 af[4], bfv[4];
    #pragma unroll
    for (int i = 0; i < 4; i++){
      af[i]  = *(const bhalf8*)(&As[buf * 128 + wr + i * 16 + l15][l4 * 8]);
      bfv[i] = *(const bhalf8*)(&Bs[buf * 256 + wc + i * 16 + l15][l4 * 8]);
    }
    #pragma unroll
    for (int i = 0; i < 4; i++)
      #pragma unroll
      for (int j = 0; j < 4; j++)
        acc[i][j] = __builtin_amdgcn_mfma_f32_16x16x32_bf16(af[i], bfv[j], acc[i][j], 0, 0, 0);
  };

  stage(0, 0);
  const int nk = K >> 5;
  int cur = 0;
  for (int kt = 0; kt < nk; ++kt){
    if (kt + 1 < nk){
      const int nxt = (cur + 1 == 3) ? 0 : cur + 1;
      stage(nxt, (kt + 1) << 5);              // prefetch next K-tile
      asm volatile("s_waitcnt vmcnt(3)" ::: "memory");  // cur done; 3 in flight
    } else {
      asm volatile("s_waitcnt vmcnt(0)" ::: "memory");  // tail: drain
    }
    __builtin_amdgcn_s_barrier();
    __builtin_amdgcn_s_setprio(1);
    domfma(cur);
    __builtin_amdgcn_s_setprio(0);
    cur = (cur + 1 == 3) ? 0 : cur + 1;
  }

  const int gm0 = by * 128 + wr, gn0 = bx * 256 + wc;
  __syncthreads();                         // all waves done with staging LDS
  if (outbf16){
    u16* sc = smem + wave * 4608;          // per-wave [64][72] u16 scratch
    #pragma unroll
    for (int i = 0; i < 4; i++){
      #pragma unroll
      for (int j = 0; j < 4; j++){
        const int gn = gn0 + j * 16 + l15;
        #pragma unroll
        for (int r = 0; r < 4; r++){
          float v = acc[i][j][r];
          if (bias) v += bias[gn];
          if (act)  v = v * (1.0f / (1.0f + __expf(-1.702f * v)));  // QuickGELU (fast exp)
          sc[(i * 16 + l4 * 4 + r) * 72 + j * 16 + l15] = f2b(v);
        }
      }
    }
    u16* Cp = (u16*)C;
    const int lr = lane >> 3, lcb = (lane & 7) * 8;
    #pragma unroll
    for (int p = 0; p < 8; p++){
      u16x8 v = *(const u16x8*)(sc + (p * 8 + lr) * 72 + lcb);
      *(u16x8*)(Cp + (size_t)(gm0 + p * 8 + lr) * N + gn0 + lcb) = v;
    }
  } else {
    float* scf = (float*)smem + wave * 2304;   // per-wave [32][72] f32 scratch
    const int rr = lane >> 4, cc = (lane & 15) * 4;
    #pragma unroll
    for (int h = 0; h < 2; h++){               // two 32-row half-tiles
      #pragma unroll
      for (int ii = 0; ii < 2; ii++){
        const int i = h * 2 + ii;
        #pragma unroll
        for (int j = 0; j < 4; j++){
          const int gn = gn0 + j * 16 + l15;
          #pragma unroll
          for (int r = 0; r < 4; r++){
            float v = acc[i][j][r];
            if (bias) v += bias[gn];
            if (act)  v = v * (1.0f / (1.0f + __expf(-1.702f * v)));
            scf[(ii * 16 + l4 * 4 + r) * 72 + j * 16 + l15] = v;
          }
        }
      }
      #pragma unroll
      for (int it = 0; it < 8; it++){
        const int row32 = it * 4 + rr;
        float4 v = *(const float4*)(scf + row32 * 72 + cc);
        const int gm = gm0 + h * 32 + row32;
        const int orow = rowperm ? ((gm & 63) * 128 + (gm >> 6)) : gm;
        if (addsrc){
          float4 a = *(const float4*)(addsrc + (size_t)orow * N + gn0 + cc);
          v.x += a.x; v.y += a.y; v.z += a.z; v.w += a.w;
        }
        *(float4*)((float*)C + (size_t)orow * N + gn0 + cc) = v;
      }
    }
  }
}

// ---- 128x128 MFMA GEMM, AMODE-1 only (fp32 vf + fused LN fallback) ----
template<int AMODE>
__global__ __launch_bounds__(256) void mgemm_k(
    const void* __restrict__ A, const u16* __restrict__ BT, void* __restrict__ C,
    int M, int N, int K,
    const float* __restrict__ bias, int act,
    const float* addsrc, int rowperm, int outbf16,
    const float2* __restrict__ stx, const float* __restrict__ gam,
    const float* __restrict__ bet)
{
  __shared__ __align__(16) u16 As[2][128][32];
  __shared__ __align__(16) u16 Bs[2][128][32];
  const int nb = N >> 7;
  const int swz = ((blockIdx.x & 7) * (gridDim.x >> 3)) + (blockIdx.x >> 3);
  const int bx = swz % nb, by = swz / nb;
  const int tid  = threadIdx.x;
  const int wave = tid >> 6, lane = tid & 63;
  const int wr = (wave >> 1) * 64, wc = (wave & 1) * 64;
  const int l15 = lane & 15, l4 = lane >> 4;
  const int srow = lane >> 2, sseg = lane & 3;
  const int sr = tid >> 2, sq = (tid & 3) * 8;

  const float* Af  = (const float*)A;

  floatx4 acc[4][4];
  #pragma unroll
  for (int i = 0; i < 4; i++)
    #pragma unroll
    for (int j = 0; j < 4; j++) acc[i][j] = (floatx4){0.f, 0.f, 0.f, 0.f};

  auto domfma = [&](int buf){
    bhalf8 af[4], bfv[4];
    #pragma unroll
    for (int i = 0; i < 4; i++){
      af[i]  = *(const bhalf8*)(&As[buf][wr + i * 16 + l15][l4 * 8]);
      bfv[i] = *(const bhalf8*)(&Bs[buf][wc + i * 16 + l15][l4 * 8]);
    }
    #pragma unroll
    for (int i = 0; i < 4; i++)
      #pragma unroll
      for (int j = 0; j < 4; j++)
        acc[i][j] = __builtin_amdgcn_mfma_f32_16x16x32_bf16(af[i], bfv[j], acc[i][j], 0, 0, 0);
  };

  {
    int   asrc[2]; float mn[2], rs[2];
    #pragma unroll
    for (int p = 0; p < 2; p++){
      int gm = by * 128 + sr + p * 64;
      asrc[p] = (gm & 255) * 128 + (gm >> 8);
      float2 s = stx[gm]; mn[p] = s.x; rs[p] = s.y;
    }
    for (int k0 = 0; k0 < K; k0 += 32){
      #pragma unroll
      for (int p = 0; p < 2; p++){
        const int r = sr + p * 64;
        const float* ap = Af + (size_t)asrc[p] * K + k0 + sq;
        float4 f0 = *(const float4*)ap, f1 = *(const float4*)(ap + 4);
        float4 g0 = *(const float4*)(gam + k0 + sq), g1 = *(const float4*)(gam + k0 + sq + 4);
        float4 e0 = *(const float4*)(bet + k0 + sq), e1 = *(const float4*)(bet + k0 + sq + 4);
        u16x8 v;
        v[0] = f2b((f0.x - mn[p]) * rs[p] * g0.x + e0.x);
        v[1] = f2b((f0.y - mn[p]) * rs[p] * g0.y + e0.y);
        v[2] = f2b((f0.z - mn[p]) * rs[p] * g0.z + e0.z);
        v[3] = f2b((f0.w - mn[p]) * rs[p] * g0.w + e0.w);
        v[4] = f2b((f1.x - mn[p]) * rs[p] * g1.x + e1.x);
        v[5] = f2b((f1.y - mn[p]) * rs[p] * g1.y + e1.y);
        v[6] = f2b((f1.z - mn[p]) * rs[p] * g1.z + e1.z);
        v[7] = f2b((f1.w - mn[p]) * rs[p] * g1.w + e1.w);
        *(u16x8*)(&As[0][r][sq]) = v;
      }
      #pragma unroll
      for (int c = 0; c < 2; c++){
        const int ch = wave * 2 + c;
        gload16(BT + (size_t)(bx * 128 + ch * 16 + srow) * K + k0 + sseg * 8,
                &Bs[0][ch * 16][0]);
      }
      __syncthreads();
      domfma(0);
      __syncthreads();
    }
  }

  const int gm0 = by * 128 + wr, gn0 = bx * 128 + wc;
  #pragma unroll
  for (int i = 0; i < 4; i++){
    #pragma unroll
    for (int r = 0; r < 4; r++){
      int gm = gm0 + i * 16 + l4 * 4 + r;
      int orow = rowperm ? ((gm & 63) * 128 + (gm >> 6)) : gm;
      #pragma unroll
      for (int j = 0; j < 4; j++){
        int gn = gn0 + j * 16 + l15;
        float v = acc[i][j][r];
        if (bias) v += bias[gn];
        if (act)  v = v * (1.0f / (1.0f + __expf(-1.702f * v)));
        if (addsrc) v += addsrc[(size_t)orow * N + gn];
        if (outbf16) ((u16*)C)[(size_t)orow * N + gn] = f2b(v);
        else         ((float*)C)[(size_t)orow * N + gn] = v;
      }
    }
  }
}

// ---- MFMA Perceiver attention: block=(bt,head), 4 waves x 16 q-rows ----
// q/kvll in combined buffer qkv512 [512][1536]: q cols [0,512),
// K at 512+h*64, V at 1024+h*64. Output staged via Ks (dead after pass 1)
// -> u16x8 vectorized stores (128B segments). Softmax uses fast __expf.
__global__ __launch_bounds__(256) void pattn_k(
    const u16* __restrict__ qc, const u16* __restrict__ kvx,
    u16* __restrict__ o)
{
  __shared__ __align__(16) u16 Ks[64][72];
  __shared__ __align__(16) u16 Vs[64][72];
  __shared__ __align__(16) u16 Ps[64][72];
  const int blk = blockIdx.x;            // bt*8 + h
  const int hh = blk & 7, bt = blk >> 3;
  const int tt = bt & 7;
  const int tid = threadIdx.x;
  const int wv = tid >> 6, ln = tid & 63;
  const int l15 = ln & 15, lg = ln >> 4;
  const int i0 = wv * 16;
  const int sj = tid >> 2, sc = (tid & 3) * 16;

  bhalf8 qf[2];
  {
    const u16* qp = qc + ((size_t)(tt * 64 + i0 + l15)) * 1536 + hh * 64 + lg * 8;
    qf[0] = *(const bhalf8*)(qp);
    qf[1] = *(const bhalf8*)(qp + 32);
  }

  floatx4 sacc[20];
  #pragma unroll
  for (int t = 0; t < 20; t++) sacc[t] = (floatx4){0.f,0.f,0.f,0.f};

  for (int ch = 0; ch < 5; ++ch){
    const u16* src = (ch < 4)
        ? (kvx + ((size_t)(bt * 256 + ch * 64 + sj)) * 1024 + hh * 64 + sc)
        : (qc  + ((size_t)(tt * 64 + sj)) * 1536 + 512 + hh * 64 + sc);
    u16x8 k0 = *(const u16x8*)(src);
    u16x8 k1 = *(const u16x8*)(src + 8);
    __syncthreads();
    *(u16x8*)(&Ks[sj][sc])     = k0;
    *(u16x8*)(&Ks[sj][sc + 8]) = k1;
    __syncthreads();
    #pragma unroll
    for (int jt = 0; jt < 4; jt++){
      bhalf8 kf0 = *(const bhalf8*)(&Ks[jt*16 + l15][lg*8]);
      bhalf8 kf1 = *(const bhalf8*)(&Ks[jt*16 + l15][32 + lg*8]);
      sacc[ch*4+jt] = __builtin_amdgcn_mfma_f32_16x16x32_bf16(qf[0], kf0, sacc[ch*4+jt], 0,0,0);
      sacc[ch*4+jt] = __builtin_amdgcn_mfma_f32_16x16x32_bf16(qf[1], kf1, sacc[ch*4+jt], 0,0,0);
    }
  }

  float inv_l[4];
  float mx[4];
  #pragma unroll
  for (int r = 0; r < 4; r++){
    float m = -1e30f;
    #pragma unroll
    for (int t = 0; t < 20; t++) m = fmaxf(m, sacc[t][r]);
    m = fmaxf(m, __shfl_xor(m, 1));
    m = fmaxf(m, __shfl_xor(m, 2));
    m = fmaxf(m, __shfl_xor(m, 4));
    m = fmaxf(m, __shfl_xor(m, 8));
    mx[r] = m;
  }
  #pragma unroll
  for (int r = 0; r < 4; r++){
    float s = 0.f;
    #pragma unroll
    for (int t = 0; t < 20; t++){
      float p = __expf(0.125f * (sacc[t][r] - mx[r]));
      sacc[t][r] = p;
      s += p;
    }
    s += __shfl_xor(s, 1); s += __shfl_xor(s, 2);
    s += __shfl_xor(s, 4); s += __shfl_xor(s, 8);
    inv_l[r] = 1.0f / s;
  }

  floatx4 oacc[4];
  #pragma unroll
  for (int dt = 0; dt < 4; dt++) oacc[dt] = (floatx4){0.f,0.f,0.f,0.f};
  for (int ch = 0; ch < 5; ++ch){
    const u16* src = (ch < 4)
        ? (kvx + ((size_t)(bt * 256 + ch * 64 + sj)) * 1024 + 512 + hh * 64 + sc)
        : (qc  + ((size_t)(tt * 64 + sj)) * 1536 + 1024 + hh * 64 + sc);
    u16x8 v0 = *(const u16x8*)(src);
    u16x8 v1 = *(const u16x8*)(src + 8);
    __syncthreads();
    #pragma unroll
    for (int e = 0; e < 8; e++) Vs[sc + e][sj]     = v0[e];
    #pragma unroll
    for (int e = 0; e < 8; e++) Vs[sc + 8 + e][sj] = v1[e];
    #pragma unroll
    for (int jt = 0; jt < 4; jt++){
      #pragma unroll
      for (int r = 0; r < 4; r++)
        Ps[i0 + 4*lg + r][jt*16 + l15] = f2b(sacc[ch*4+jt][r]);
    }
    __syncthreads();
    #pragma unroll
    for (int kk = 0; kk < 2; kk++){
      bhalf8 pf = *(const bhalf8*)(&Ps[i0 + l15][kk*32 + lg*8]);
      #pragma unroll
      for (int dt = 0; dt < 4; dt++){
        bhalf8 vfr = *(const bhalf8*)(&Vs[dt*16 + l15][kk*32 + lg*8]);
        oacc[dt] = __builtin_amdgcn_mfma_f32_16x16x32_bf16(pf, vfr, oacc[dt], 0,0,0);
      }
    }
  }

  // ---- vectorized epilogue via Ks scratch (dead after pass 1) ----
  #pragma unroll
  for (int dt = 0; dt < 4; dt++)
    #pragma unroll
    for (int r = 0; r < 4; r++)
      Ks[i0 + 4*lg + r][dt*16 + l15] = f2b(oacc[dt][r] * inv_l[r]);
  const int lr = ln >> 3, lcb = (ln & 7) * 8;
  #pragma unroll
  for (int p = 0; p < 2; p++){
    const int row = i0 + p * 8 + lr;
    u16x8 v = *(const u16x8*)(&Ks[row][lcb]);
    *(u16x8*)(o + ((size_t)(bt * 64 + row)) * 512 + hh * 64 + lcb) = v;
  }
}

// ---- MFMA self-attention: block=(bt,head), 4 waves x 16 q-rows, 64 keys ----
__global__ __launch_bounds__(256) void sattn_k(
    const u16* __restrict__ qkv, u16* __restrict__ o2)
{
  __shared__ __align__(16) u16 Ks[64][72];
  __shared__ __align__(16) u16 Vs[64][72];
  __shared__ __align__(16) u16 Ps[64][72];
  const int blk = blockIdx.x;
  const int hh = blk % 12, bt = blk / 12;
  const int tid = threadIdx.x;
  const int wv = tid >> 6, ln = tid & 63;
  const int l15 = ln & 15, lg = ln >> 4;
  const int i0 = wv * 16;
  const int sj = tid >> 2, sc = (tid & 3) * 16;

  const u16* kp = qkv + ((size_t)sj * 128 + bt) * 2304 + 768 + hh * 64 + sc;
  u16x8 k0 = *(const u16x8*)(kp);
  u16x8 k1 = *(const u16x8*)(kp + 8);
  u16x8 v0 = *(const u16x8*)(kp + 768);
  u16x8 v1 = *(const u16x8*)(kp + 776);
  *(u16x8*)(&Ks[sj][sc])     = k0;
  *(u16x8*)(&Ks[sj][sc + 8]) = k1;
  #pragma unroll
  for (int e = 0; e < 8; e++) Vs[sc + e][sj]     = v0[e];
  #pragma unroll
  for (int e = 0; e < 8; e++) Vs[sc + 8 + e][sj] = v1[e];

  bhalf8 qf[2];
  {
    const u16* qp = qkv + ((size_t)(i0 + l15) * 128 + bt) * 2304 + hh * 64 + lg * 8;
    qf[0] = *(const bhalf8*)(qp);
    qf[1] = *(const bhalf8*)(qp + 32);
  }
  __syncthreads();

  floatx4 sacc[4];
  #pragma unroll
  for (int t = 0; t < 4; t++) sacc[t] = (floatx4){0.f,0.f,0.f,0.f};
  #pragma unroll
  for (int jt = 0; jt < 4; jt++){
    bhalf8 kf0 = *(const bhalf8*)(&Ks[jt*16 + l15][lg*8]);
    bhalf8 kf1 = *(const bhalf8*)(&Ks[jt*16 + l15][32 + lg*8]);
    sacc[jt] = __builtin_amdgcn_mfma_f32_16x16x32_bf16(qf[0], kf0, sacc[jt], 0,0,0);
    sacc[jt] = __builtin_amdgcn_mfma_f32_16x16x32_bf16(qf[1], kf1, sacc[jt], 0,0,0);
  }

  float inv_l[4];
  #pragma unroll
  for (int r = 0; r < 4; r++){
    float m = -1e30f;
    #pragma unroll
    for (int t = 0; t < 4; t++) m = fmaxf(m, sacc[t][r]);
    m = fmaxf(m, __shfl_xor(m, 1));
    m = fmaxf(m, __shfl_xor(m, 2));
    m = fmaxf(m, __shfl_xor(m, 4));
    m = fmaxf(m, __shfl_xor(m, 8));
    float s = 0.f;
    #pragma unroll
    for (int t = 0; t < 4; t++){
      float p = __expf(0.125f * (sacc[t][r] - m));
      sacc[t][r] = p;
      s += p;
    }
    s += __shfl_xor(s, 1); s += __shfl_xor(s, 2);
    s += __shfl_xor(s, 4); s += __shfl_xor(s, 8);
    inv_l[r] = 1.0f / s;
  }

  #pragma unroll
  for (int jt = 0; jt < 4; jt++){
    #pragma unroll
    for (int r = 0; r < 4; r++)
      Ps[i0 + 4*lg + r][jt*16 + l15] = f2b(sacc[jt][r]);
  }
  __syncthreads();

  floatx4 oacc[4];
  #pragma unroll
  for (int dt = 0; dt < 4; dt++) oacc[dt] = (floatx4){0.f,0.f,0.f,0.f};
  #pragma unroll
  for (int kk = 0; kk < 2; kk++){
    bhalf8 pf = *(const bhalf8*)(&Ps[i0 + l15][kk*32 + lg*8]);
    #pragma unroll
    for (int dt = 0; dt < 4; dt++){
      bhalf8 vfr = *(const bhalf8*)(&Vs[dt*16 + l15][kk*32 + lg*8]);
      oacc[dt] = __builtin_amdgcn_mfma_f32_16x16x32_bf16(pf, vfr, oacc[dt], 0,0,0);
    }
  }

  // ---- vectorized epilogue via Ks scratch (dead after QK^T) ----
  #pragma unroll
  for (int dt = 0; dt < 4; dt++)
    #pragma unroll
    for (int r = 0; r < 4; r++)
      Ks[i0 + 4*lg + r][dt*16 + l15] = f2b(oacc[dt][r] * inv_l[r]);
  const int lr = ln >> 3, lcb = (ln & 7) * 8;
  #pragma unroll
  for (int p = 0; p < 2; p++){
    const int row = i0 + p * 8 + lr;
    u16x8 v = *(const u16x8*)(&Ks[row][lcb]);
    *(u16x8*)(o2 + ((size_t)(row * 128 + bt)) * 768 + hh * 64 + lcb) = v;
  }
}

extern "C" void kernel_launch(void* const* d_in, const int* in_sizes, int n_in,
                              void* d_out, int out_size, void* d_ws, size_t ws_size,
                              hipStream_t stream)
{
  const float* vf   = (const float*)d_in[0];
  const float* lat  = (const float*)d_in[1];
  const float* nl0g = (const float*)d_in[2];
  const float* nl0b = (const float*)d_in[3];
  const float* pmg  = (const float*)d_in[4];
  const float* pmb  = (const float*)d_in[5];
  const float* plg  = (const float*)d_in[6];
  const float* plb  = (const float*)d_in[7];
  const float* Wq   = (const float*)d_in[8];
  const float* Wkv  = (const float*)d_in[9];
  const float* Wo   = (const float*)d_in[10];
  const float* ln1g = (const float*)d_in[11];
  const float* ln1b = (const float*)d_in[12];
  const float* Wqkv = (const float*)d_in[13];
  const float* bqkv = (const float*)d_in[14];
  const float* Wout = (const float*)d_in[15];
  const float* bout = (const float*)d_in[16];
  const float* ln2g = (const float*)d_in[17];
  const float* ln2b = (const float*)d_in[18];
  const float* Wfc  = (const float*)d_in[19];
  const float* bfc  = (const float*)d_in[20];
  const float* Wpr  = (const float*)d_in[21];
  const float* bpr  = (const float*)d_in[22];

  // ---- ws layout: base high-water 104,857,600 B; optional xm at 117.4M ----
  char* ws = (char*)d_ws;
  u16*    kvx    = (u16*)(ws + 0);          // 67,108,864 (dead after pattn)
  u16*    qkvb   = (u16*)(ws + 0);          // 37,748,736 (dead after sattn)
  u16*    o2b    = (u16*)(ws + 37748736);   // 12,582,912 (dead after Wout gemm)
  u16*    hb     = (u16*)(ws + 0);          // 50,331,648
  u16*    WoT    = (u16*)(ws + 50331648);
  u16*    WqkvT  = (u16*)(ws + 51118080);
  u16*    WoutT  = (u16*)(ws + 54657024);
  u16*    WfcT   = (u16*)(ws + 55836672);
  u16*    WprT   = (u16*)(ws + 60555264);   // ends 65,273,856
  u16*    WqT    = (u16*)(ws + 67108864);   // [512][768] then WkvT contiguous
  u16*    WkvT   = (u16*)(ws + 67895296);   // ends 69,468,160
  float*  yb     = (float*)(ws + 67108864); // written after WqT/WkvT dead
  u16*    llb    = (u16*)(ws + 92274688);
  u16*    qkv512 = (u16*)(ws + 93323264);   // [512][1536] bf16 (q|K|V)
  u16*    ob     = (u16*)(ws + 95420416);   // ends 103,809,024
  u16*    zb     = (u16*)(ws + 92274688);   // overlays llb..ob when dead
  u16*    xm     = (u16*)(ws + 117440512);  // 50,331,648, ends 167,772,160
  float2* stx    = (float2*)(ws + 93061120);
  const bool use_xm = (ws_size >= 167772160ull);

  const float* nof = nullptr;
  const float2* nos = nullptr;

  // early transposes: Wq (384 blks) + Wkv (768 blks) in ONE launch
  hipLaunchKernelGGL(transpB_k, dim3(1152), dim3(256), 0, stream,
                     Wq,  WqT,  768, 512,  384,
                     Wkv, WkvT, 768, 1024, 1152,
                     Wkv, WkvT, 768, 1024, 1152,
                     Wkv, WkvT, 768, 1024, 1152,
                     Wkv, WkvT, 768, 1024, 1152);
  hipLaunchKernelGGL(ln_lat2_k, dim3(512), dim3(256), 0, stream,
                     lat, llb, nl0g, nl0b, plg, plb);
  // q|kv_ll = ll @ [Wq|Wkv]: grid 4x6 = 24 blocks
  hipLaunchKernelGGL(mgemmW_k, dim3(24), dim3(512), 0, stream,
                     llb, WqT, (void*)qkv512, 512, 1536, 768, nof, 0, nof, 0, 1);
  if (use_xm){
    hipLaunchKernelGGL(ln_x_k, dim3(8192), dim3(256), 0, stream, vf, xm, pmg, pmb);
    // kv_x: 256x4 = 1024 blocks
    hipLaunchKernelGGL(mgemmW_k, dim3(1024), dim3(512), 0, stream,
                       xm, WkvT, (void*)kvx, 32768, 1024, 768, nof, 0, nof, 0, 1);
  } else {
    hipLaunchKernelGGL(stats_x_k, dim3(32768), dim3(256), 0, stream, vf, stx);
    hipLaunchKernelGGL(mgemm_k<1>, dim3(2048), dim3(256), 0, stream,
                       (const void*)vf, WkvT, (void*)kvx, 32768, 1024, 768,
                       nof, 0, nof, 0, 1, stx, pmg, pmb);
  }
  hipLaunchKernelGGL(pattn_k, dim3(1024), dim3(256), 0, stream, qkv512, kvx, ob);
  // late transposes in ONE launch
  hipLaunchKernelGGL(transpB_k, dim3(7296), dim3(256), 0, stream,
                     Wo,   WoT,   512,  768,  384,
                     Wqkv, WqkvT, 768,  2304, 2112,
                     Wout, WoutT, 768,  768,  2688,
                     Wfc,  WfcT,  768,  3072, 4992,
                     Wpr,  WprT,  3072, 768,  7296);
  // y = rearrange(ob @ Wo): 192 blocks (f32 out, rowperm)
  hipLaunchKernelGGL(mgemmW_k, dim3(192), dim3(512), 0, stream,
                     ob, WoT, (void*)yb, 8192, 768, 512, nof, 0, nof, 1, 0);
  hipLaunchKernelGGL(ln_f32_k, dim3(2048), dim3(256), 0, stream, yb, zb, ln1g, ln1b);
  // qkv: 576 blocks
  hipLaunchKernelGGL(mgemmW_k, dim3(576), dim3(512), 0, stream,
                     zb, WqkvT, (void*)qkvb, 8192, 2304, 768, bqkv, 0, nof, 0, 1);
  hipLaunchKernelGGL(sattn_k, dim3(1536), dim3(256), 0, stream, qkvb, o2b);
  // y += o2 @ Wout: 192 (f32 out, addsrc)
  hipLaunchKernelGGL(mgemmW_k, dim3(192), dim3(512), 0, stream,
                     o2b, WoutT, (void*)yb, 8192, 768, 768, bout, 0, yb, 0, 0);
  hipLaunchKernelGGL(ln_f32_k, dim3(2048), dim3(256), 0, stream, yb, zb, ln2g, ln2b);
  // h = QuickGELU(z2 @ fc): 768 blocks
  hipLaunchKernelGGL(mgemmW_k, dim3(768), dim3(512), 0, stream,
                     zb, WfcT, (void*)hb, 8192, 3072, 768, bfc, 1, nof, 0, 1);
  // out = y + h @ proj: 192 (K=3072, f32 out, addsrc)
  hipLaunchKernelGGL(mgemmW_k, dim3(192), dim3(512), 0, stream,
                     hb, WprT, d_out, 8192, 768, 3072, bpr, 0, yb, 0, 0);
}

// Round 24
// 391.460 us; speedup vs baseline: 1.0285x; 1.0011x over previous
//
#include <hip/hip_runtime.h>
#include <hip/hip_bf16.h>
#include <cstdint>
#include <cstddef>

typedef unsigned short u16;
typedef __bf16 bhalf8 __attribute__((ext_vector_type(8)));
typedef float floatx4 __attribute__((ext_vector_type(4)));
typedef unsigned short u16x8 __attribute__((ext_vector_type(8)));

__device__ __forceinline__ float b2f(u16 u){
  union { uint32_t i; float f; } x; x.i = ((uint32_t)u) << 16; return x.f;
}
__device__ __forceinline__ u16 f2b(float f){
  uint32_t i = __float_as_uint(f);
  uint32_t r = (i + 0x7FFFu + ((i >> 16) & 1u)) >> 16;   // round-nearest-even
  return (u16)r;
}

// async global->LDS DMA, 16B per lane; LDS dest = wave-uniform base + lane*16
__device__ __forceinline__ void gload16(const u16* g, u16* l){
  __builtin_amdgcn_global_load_lds(
      (const __attribute__((address_space(1))) uint32_t*)g,
      (__attribute__((address_space(3))) uint32_t*)l, 16, 0, 0);
}

// ---- block-wide sum over 256 threads (4 waves) ----
__device__ __forceinline__ float block_sum256(float v, float* sh){
  #pragma unroll
  for (int o = 32; o > 0; o >>= 1) v += __shfl_down(v, o);
  __syncthreads();
  if ((threadIdx.x & 63u) == 0) sh[threadIdx.x >> 6] = v;
  __syncthreads();
  return sh[0] + sh[1] + sh[2] + sh[3];
}

// ---- wave-wide sum over 64 lanes ----
__device__ __forceinline__ float wave_sum(float v){
  #pragma unroll
  for (int o = 32; o > 0; o >>= 1) v += __shfl_xor(v, o);
  return v;
}

// ---- per-row LN stats of visual_feat (fp32), rearranged row order ----
__global__ __launch_bounds__(256) void stats_x_k(
    const float* __restrict__ vf, float2* __restrict__ st)
{
  __shared__ float sh[4];
  const int r  = blockIdx.x;
  const int nn = r & 255, bt = r >> 8;
  const float* in = vf + ((size_t)nn * 128 + bt) * 768;
  const int t = threadIdx.x;
  float v0 = in[t], v1 = in[t + 256], v2 = in[t + 512];
  float mean = block_sum256(v0 + v1 + v2, sh) * (1.0f / 768.0f);
  float d0 = v0 - mean, d1 = v1 - mean, d2 = v2 - mean;
  float var = block_sum256(d0*d0 + d1*d1 + d2*d2, sh) * (1.0f / 768.0f);
  if (t == 0) st[r] = make_float2(mean, rsqrtf(var + 1e-5f));
}

// ---- LN of visual_feat -> bf16 xm, rearranged rows; ONE WAVE PER ROW ----
__global__ __launch_bounds__(256) void ln_x_k(
    const float* __restrict__ vf, u16* __restrict__ xm,
    const float* __restrict__ g, const float* __restrict__ b)
{
  const int r  = blockIdx.x * 4 + (threadIdx.x >> 6);  // output row
  const int ln = threadIdx.x & 63;
  const int nn = r & 255, bt = r >> 8;
  const float* in = vf + ((size_t)nn * 128 + bt) * 768;
  float4 v[3];
  #pragma unroll
  for (int i = 0; i < 3; i++) v[i] = *(const float4*)(in + i * 256 + ln * 4);
  float s = 0.f;
  #pragma unroll
  for (int i = 0; i < 3; i++) s += v[i].x + v[i].y + v[i].z + v[i].w;
  const float mean = wave_sum(s) * (1.0f / 768.0f);
  float q = 0.f;
  #pragma unroll
  for (int i = 0; i < 3; i++){
    float dx = v[i].x - mean, dy = v[i].y - mean, dz = v[i].z - mean, dw = v[i].w - mean;
    q += dx*dx + dy*dy + dz*dz + dw*dw;
  }
  const float rs = rsqrtf(wave_sum(q) * (1.0f / 768.0f) + 1e-5f);
  #pragma unroll
  for (int i = 0; i < 3; i++){
    const int c = i * 256 + ln * 4;
    float4 gv = *(const float4*)(g + c);
    float4 bv = *(const float4*)(b + c);
    ushort4 o;
    o.x = f2b((v[i].x - mean) * rs * gv.x + bv.x);
    o.y = f2b((v[i].y - mean) * rs * gv.y + bv.y);
    o.z = f2b((v[i].z - mean) * rs * gv.z + bv.z);
    o.w = f2b((v[i].w - mean) * rs * gv.w + bv.w);
    *(ushort4*)(xm + (size_t)r * 768 + c) = o;
  }
}

// ---- double LayerNorm of latents (fp32 in) -> bf16 ----
__global__ __launch_bounds__(256) void ln_lat2_k(
    const float* __restrict__ lat, u16* __restrict__ ll,
    const float* __restrict__ g0, const float* __restrict__ b0,
    const float* __restrict__ g1, const float* __restrict__ b1)
{
  __shared__ float sh[4];
  const int r = blockIdx.x;
  const int t = threadIdx.x;
  const float* in = lat + (size_t)r * 768;
  float v[3];
  #pragma unroll
  for (int i = 0; i < 3; i++) v[i] = in[t + 256 * i];
  #pragma unroll
  for (int pass = 0; pass < 2; ++pass){
    float mean = block_sum256(v[0] + v[1] + v[2], sh) * (1.0f / 768.0f);
    float d0 = v[0] - mean, d1 = v[1] - mean, d2 = v[2] - mean;
    float var = block_sum256(d0*d0 + d1*d1 + d2*d2, sh) * (1.0f / 768.0f);
    float rs = rsqrtf(var + 1e-5f);
    const float* g = pass ? g1 : g0;
    const float* b = pass ? b1 : b0;
    #pragma unroll
    for (int i = 0; i < 3; i++){
      int c = t + 256 * i;
      v[i] = (v[i] - mean) * rs * g[c] + b[c];
    }
  }
  #pragma unroll
  for (int i = 0; i < 3; i++) ll[(size_t)r * 768 + t + 256 * i] = f2b(v[i]);
}

// ---- LN of fp32 ws rows -> bf16; ONE WAVE PER ROW (4 rows/block) ----
__global__ __launch_bounds__(256) void ln_f32_k(
    const float* __restrict__ y, u16* __restrict__ z,
    const float* __restrict__ g, const float* __restrict__ b)
{
  const int r  = blockIdx.x * 4 + (threadIdx.x >> 6);
  const int ln = threadIdx.x & 63;
  const float* in = y + (size_t)r * 768;
  float4 v[3];
  #pragma unroll
  for (int i = 0; i < 3; i++) v[i] = *(const float4*)(in + i * 256 + ln * 4);
  float s = 0.f;
  #pragma unroll
  for (int i = 0; i < 3; i++) s += v[i].x + v[i].y + v[i].z + v[i].w;
  const float mean = wave_sum(s) * (1.0f / 768.0f);
  float q = 0.f;
  #pragma unroll
  for (int i = 0; i < 3; i++){
    float dx = v[i].x - mean, dy = v[i].y - mean, dz = v[i].z - mean, dw = v[i].w - mean;
    q += dx*dx + dy*dy + dz*dz + dw*dw;
  }
  const float rs = rsqrtf(wave_sum(q) * (1.0f / 768.0f) + 1e-5f);
  #pragma unroll
  for (int i = 0; i < 3; i++){
    const int c = i * 256 + ln * 4;
    float4 gv = *(const float4*)(g + c);
    float4 bv = *(const float4*)(b + c);
    ushort4 o;
    o.x = f2b((v[i].x - mean) * rs * gv.x + bv.x);
    o.y = f2b((v[i].y - mean) * rs * gv.y + bv.y);
    o.z = f2b((v[i].z - mean) * rs * gv.z + bv.z);
    o.w = f2b((v[i].w - mean) * rs * gv.w + bv.w);
    *(ushort4*)(z + (size_t)r * 768 + c) = o;
  }
}

// ---- batched weight transpose + bf16 convert: up to 5 matrices per launch ----
__global__ __launch_bounds__(256) void transpB_k(
    const float* s0, u16* d0, int K0, int N0, int e0,
    const float* s1, u16* d1, int K1, int N1, int e1,
    const float* s2, u16* d2, int K2, int N2, int e2,
    const float* s3, u16* d3, int K3, int N3, int e3,
    const float* s4, u16* d4, int K4, int N4, int e4)
{
  __shared__ u16 sh[32][33];
  const int b = blockIdx.x;
  const float* src; u16* dst; int K, N, base;
  if      (b < e0){ src = s0; dst = d0; K = K0; N = N0; base = 0;  }
  else if (b < e1){ src = s1; dst = d1; K = K1; N = N1; base = e0; }
  else if (b < e2){ src = s2; dst = d2; K = K2; N = N2; base = e1; }
  else if (b < e3){ src = s3; dst = d3; K = K3; N = N3; base = e2; }
  else            { src = s4; dst = d4; K = K4; N = N4; base = e3; }
  const int lb = b - base;
  const int nb = N >> 5;
  const int bx = lb % nb, byy = lb / nb;
  const int tx = threadIdx.x & 31, ty = threadIdx.x >> 5;
  #pragma unroll
  for (int i = 0; i < 4; i++){
    int k = byy * 32 + ty + i * 8, n = bx * 32 + tx;
    sh[tx][ty + i * 8] = f2b(src[(size_t)k * N + n]);
  }
  __syncthreads();
  #pragma unroll
  for (int i = 0; i < 4; i++){
    int n = bx * 32 + ty + i * 8, k = byy * 32 + tx;
    dst[(size_t)n * K + k] = sh[ty + i * 8][tx];
  }
}

// ---- 128x256 MFMA GEMM (R19-proven): 8 waves x (64x64), 3-buffer rotation,
// ONE barrier per K-step, counted vmcnt(3); LDS-staged vectorized epilogues.
__global__ __launch_bounds__(512) void mgemmW_k(
    const u16* __restrict__ A, const u16* __restrict__ BT, void* __restrict__ C,
    int M, int N, int K,
    const float* __restrict__ bias, int act,
    const float* addsrc, int rowperm, int outbf16)
{
  __shared__ __align__(16) u16 smem[36864];      // 73,728 B
  u16 (*As)[32] = (u16 (*)[32])smem;             // [3*128][32]
  u16 (*Bs)[32] = (u16 (*)[32])(smem + 12288);   // [3*256][32]
  const int nb = N >> 8;
  const int swz = ((blockIdx.x & 7) * (gridDim.x >> 3)) + (blockIdx.x >> 3);
  const int bx = swz % nb, by = swz / nb;
  const int tid = threadIdx.x;
  const int wave = tid >> 6, lane = tid & 63;
  const int wr = (wave >> 2) * 64;        // M-half
  const int wc = (wave & 3) * 64;         // N-quarter
  const int l15 = lane & 15, l4 = lane >> 4;
  const int srow = lane >> 2, sseg = lane & 3;   // staging: 16 rows x 4 segs

  floatx4 acc[4][4];
  #pragma unroll
  for (int i = 0; i < 4; i++)
    #pragma unroll
    for (int j = 0; j < 4; j++) acc[i][j] = (floatx4){0.f, 0.f, 0.f, 0.f};

  auto stage = [&](int buf, int k0){
    gload16(A + (size_t)(by * 128 + wave * 16 + srow) * K + k0 + sseg * 8,
            &As[buf * 128 + wave * 16][0]);
    #pragma unroll
    for (int c = 0; c < 2; c++){
      gload16(BT + (size_t)(bx * 256 + wave * 32 + c * 16 + srow) * K + k0 + sseg * 8,
              &Bs[buf * 256 + wave * 32 + c * 16][0]);
    }
  };
  auto domfma = [&](int buf){
    bhalf8 af[4], bfv[4];
    #pragma unroll
    for (int i = 0; i < 4; i++){
      af[i]  = *(const bhalf8*)(&As[buf * 128 + wr + i * 16 + l15][l4 * 8]);
      bfv[i] = *(const bhalf8*)(&Bs[buf * 256 + wc + i * 16 + l15][l4 * 8]);
    }
    #pragma unroll
    for (int i = 0; i < 4; i++)
      #pragma unroll
      for (int j = 0; j < 4; j++)
        acc[i][j] = __builtin_amdgcn_mfma_f32_16x16x32_bf16(af[i], bfv[j], acc[i][j], 0, 0, 0);
  };

  stage(0, 0);
  const int nk = K >> 5;
  int cur = 0;
  for (int kt = 0; kt < nk; ++kt){
    if (kt + 1 < nk){
      const int nxt = (cur + 1 == 3) ? 0 : cur + 1;
      stage(nxt, (kt + 1) << 5);              // prefetch next K-tile
      asm volatile("s_waitcnt vmcnt(3)" ::: "memory");  // cur done; 3 in flight
    } else {
      asm volatile("s_waitcnt vmcnt(0)" ::: "memory");  // tail: drain
    }
    __builtin_amdgcn_s_barrier();
    __builtin_amdgcn_s_setprio(1);
    domfma(cur);
    __builtin_amdgcn_s_setprio(0);
    cur = (cur + 1 == 3) ? 0 : cur + 1;
  }

  const int gm0 = by * 128 + wr, gn0 = bx * 256 + wc;
  __syncthreads();                         // all waves done with staging LDS
  if (outbf16){
    u16* sc = smem + wave * 4608;          // per-wave [64][72] u16 scratch
    #pragma unroll
    for (int i = 0; i < 4; i++){
      #pragma unroll
      for (int j = 0; j < 4; j++){
        const int gn = gn0 + j * 16 + l15;
        #pragma unroll
        for (int r = 0; r < 4; r++){
          float v = acc[i][j][r];
          if (bias) v += bias[gn];
          if (act)  v = v * (1.0f / (1.0f + __expf(-1.702f * v)));  // QuickGELU (fast exp)
          sc[(i * 16 + l4 * 4 + r) * 72 + j * 16 + l15] = f2b(v);
        }
      }
    }
    u16* Cp = (u16*)C;
    const int lr = lane >> 3, lcb = (lane & 7) * 8;
    #pragma unroll
    for (int p = 0; p < 8; p++){
      u16x8 v = *(const u16x8*)(sc + (p * 8 + lr) * 72 + lcb);
      *(u16x8*)(Cp + (size_t)(gm0 + p * 8 + lr) * N + gn0 + lcb) = v;
    }
  } else {
    float* scf = (float*)smem + wave * 2304;   // per-wave [32][72] f32 scratch
    const int rr = lane >> 4, cc = (lane & 15) * 4;
    #pragma unroll
    for (int h = 0; h < 2; h++){               // two 32-row half-tiles
      #pragma unroll
      for (int ii = 0; ii < 2; ii++){
        const int i = h * 2 + ii;
        #pragma unroll
        for (int j = 0; j < 4; j++){
          const int gn = gn0 + j * 16 + l15;
          #pragma unroll
          for (int r = 0; r < 4; r++){
            float v = acc[i][j][r];
            if (bias) v += bias[gn];
            if (act)  v = v * (1.0f / (1.0f + __expf(-1.702f * v)));
            scf[(ii * 16 + l4 * 4 + r) * 72 + j * 16 + l15] = v;
          }
        }
      }
      #pragma unroll
      for (int it = 0; it < 8; it++){
        const int row32 = it * 4 + rr;
        float4 v = *(const float4*)(scf + row32 * 72 + cc);
        const int gm = gm0 + h * 32 + row32;
        const int orow = rowperm ? ((gm & 63) * 128 + (gm >> 6)) : gm;
        if (addsrc){
          float4 a = *(const float4*)(addsrc + (size_t)orow * N + gn0 + cc);
          v.x += a.x; v.y += a.y; v.z += a.z; v.w += a.w;
        }
        *(float4*)((float*)C + (size_t)orow * N + gn0 + cc) = v;
      }
    }
  }
}

// ---- 128x128 MFMA GEMM, AMODE-1 only (fp32 vf + fused LN fallback) ----
template<int AMODE>
__global__ __launch_bounds__(256) void mgemm_k(
    const void* __restrict__ A, const u16* __restrict__ BT, void* __restrict__ C,
    int M, int N, int K,
    const float* __restrict__ bias, int act,
    const float* addsrc, int rowperm, int outbf16,
    const float2* __restrict__ stx, const float* __restrict__ gam,
    const float* __restrict__ bet)
{
  __shared__ __align__(16) u16 As[2][128][32];
  __shared__ __align__(16) u16 Bs[2][128][32];
  const int nb = N >> 7;
  const int swz = ((blockIdx.x & 7) * (gridDim.x >> 3)) + (blockIdx.x >> 3);
  const int bx = swz % nb, by = swz / nb;
  const int tid  = threadIdx.x;
  const int wave = tid >> 6, lane = tid & 63;
  const int wr = (wave >> 1) * 64, wc = (wave & 1) * 64;
  const int l15 = lane & 15, l4 = lane >> 4;
  const int srow = lane >> 2, sseg = lane & 3;
  const int sr = tid >> 2, sq = (tid & 3) * 8;

  const float* Af  = (const float*)A;

  floatx4 acc[4][4];
  #pragma unroll
  for (int i = 0; i < 4; i++)
    #pragma unroll
    for (int j = 0; j < 4; j++) acc[i][j] = (floatx4){0.f, 0.f, 0.f, 0.f};

  auto domfma = [&](int buf){
    bhalf8 af[4], bfv[4];
    #pragma unroll
    for (int i = 0; i < 4; i++){
      af[i]  = *(const bhalf8*)(&As[buf][wr + i * 16 + l15][l4 * 8]);
      bfv[i] = *(const bhalf8*)(&Bs[buf][wc + i * 16 + l15][l4 * 8]);
    }
    #pragma unroll
    for (int i = 0; i < 4; i++)
      #pragma unroll
      for (int j = 0; j < 4; j++)
        acc[i][j] = __builtin_amdgcn_mfma_f32_16x16x32_bf16(af[i], bfv[j], acc[i][j], 0, 0, 0);
  };

  {
    int   asrc[2]; float mn[2], rs[2];
    #pragma unroll
    for (int p = 0; p < 2; p++){
      int gm = by * 128 + sr + p * 64;
      asrc[p] = (gm & 255) * 128 + (gm >> 8);
      float2 s = stx[gm]; mn[p] = s.x; rs[p] = s.y;
    }
    for (int k0 = 0; k0 < K; k0 += 32){
      #pragma unroll
      for (int p = 0; p < 2; p++){
        const int r = sr + p * 64;
        const float* ap = Af + (size_t)asrc[p] * K + k0 + sq;
        float4 f0 = *(const float4*)ap, f1 = *(const float4*)(ap + 4);
        float4 g0 = *(const float4*)(gam + k0 + sq), g1 = *(const float4*)(gam + k0 + sq + 4);
        float4 e0 = *(const float4*)(bet + k0 + sq), e1 = *(const float4*)(bet + k0 + sq + 4);
        u16x8 v;
        v[0] = f2b((f0.x - mn[p]) * rs[p] * g0.x + e0.x);
        v[1] = f2b((f0.y - mn[p]) * rs[p] * g0.y + e0.y);
        v[2] = f2b((f0.z - mn[p]) * rs[p] * g0.z + e0.z);
        v[3] = f2b((f0.w - mn[p]) * rs[p] * g0.w + e0.w);
        v[4] = f2b((f1.x - mn[p]) * rs[p] * g1.x + e1.x);
        v[5] = f2b((f1.y - mn[p]) * rs[p] * g1.y + e1.y);
        v[6] = f2b((f1.z - mn[p]) * rs[p] * g1.z + e1.z);
        v[7] = f2b((f1.w - mn[p]) * rs[p] * g1.w + e1.w);
        *(u16x8*)(&As[0][r][sq]) = v;
      }
      #pragma unroll
      for (int c = 0; c < 2; c++){
        const int ch = wave * 2 + c;
        gload16(BT + (size_t)(bx * 128 + ch * 16 + srow) * K + k0 + sseg * 8,
                &Bs[0][ch * 16][0]);
      }
      __syncthreads();
      domfma(0);
      __syncthreads();
    }
  }

  const int gm0 = by * 128 + wr, gn0 = bx * 128 + wc;
  #pragma unroll
  for (int i = 0; i < 4; i++){
    #pragma unroll
    for (int r = 0; r < 4; r++){
      int gm = gm0 + i * 16 + l4 * 4 + r;
      int orow = rowperm ? ((gm & 63) * 128 + (gm >> 6)) : gm;
      #pragma unroll
      for (int j = 0; j < 4; j++){
        int gn = gn0 + j * 16 + l15;
        float v = acc[i][j][r];
        if (bias) v += bias[gn];
        if (act)  v = v * (1.0f / (1.0f + __expf(-1.702f * v)));
        if (addsrc) v += addsrc[(size_t)orow * N + gn];
        if (outbf16) ((u16*)C)[(size_t)orow * N + gn] = f2b(v);
        else         ((float*)C)[(size_t)orow * N + gn] = v;
      }
    }
  }
}

// ---- MFMA Perceiver attention: HEAD-MAJOR blocks (blk = h*128 + bt) so all
// 8 heads sharing one bt's KV tile land on the same XCD (T1 locality).
// q/kvll in combined buffer qkv512 [512][1536]: q cols [0,512),
// K at 512+h*64, V at 1024+h*64. Vectorized epilogue via Ks scratch.
__global__ __launch_bounds__(256) void pattn_k(
    const u16* __restrict__ qc, const u16* __restrict__ kvx,
    u16* __restrict__ o)
{
  __shared__ __align__(16) u16 Ks[64][72];
  __shared__ __align__(16) u16 Vs[64][72];
  __shared__ __align__(16) u16 Ps[64][72];
  const int blk = blockIdx.x;            // h*128 + bt  (head-major)
  const int hh = blk >> 7, bt = blk & 127;
  const int tt = bt & 7;
  const int tid = threadIdx.x;
  const int wv = tid >> 6, ln = tid & 63;
  const int l15 = ln & 15, lg = ln >> 4;
  const int i0 = wv * 16;
  const int sj = tid >> 2, sc = (tid & 3) * 16;

  bhalf8 qf[2];
  {
    const u16* qp = qc + ((size_t)(tt * 64 + i0 + l15)) * 1536 + hh * 64 + lg * 8;
    qf[0] = *(const bhalf8*)(qp);
    qf[1] = *(const bhalf8*)(qp + 32);
  }

  floatx4 sacc[20];
  #pragma unroll
  for (int t = 0; t < 20; t++) sacc[t] = (floatx4){0.f,0.f,0.f,0.f};

  for (int ch = 0; ch < 5; ++ch){
    const u16* src = (ch < 4)
        ? (kvx + ((size_t)(bt * 256 + ch * 64 + sj)) * 1024 + hh * 64 + sc)
        : (qc  + ((size_t)(tt * 64 + sj)) * 1536 + 512 + hh * 64 + sc);
    u16x8 k0 = *(const u16x8*)(src);
    u16x8 k1 = *(const u16x8*)(src + 8);
    __syncthreads();
    *(u16x8*)(&Ks[sj][sc])     = k0;
    *(u16x8*)(&Ks[sj][sc + 8]) = k1;
    __syncthreads();
    #pragma unroll
    for (int jt = 0; jt < 4; jt++){
      bhalf8 kf0 = *(const bhalf8*)(&Ks[jt*16 + l15][lg*8]);
      bhalf8 kf1 = *(const bhalf8*)(&Ks[jt*16 + l15][32 + lg*8]);
      sacc[ch*4+jt] = __builtin_amdgcn_mfma_f32_16x16x32_bf16(qf[0], kf0, sacc[ch*4+jt], 0,0,0);
      sacc[ch*4+jt] = __builtin_amdgcn_mfma_f32_16x16x32_bf16(qf[1], kf1, sacc[ch*4+jt], 0,0,0);
    }
  }

  float inv_l[4];
  float mx[4];
  #pragma unroll
  for (int r = 0; r < 4; r++){
    float m = -1e30f;
    #pragma unroll
    for (int t = 0; t < 20; t++) m = fmaxf(m, sacc[t][r]);
    m = fmaxf(m, __shfl_xor(m, 1));
    m = fmaxf(m, __shfl_xor(m, 2));
    m = fmaxf(m, __shfl_xor(m, 4));
    m = fmaxf(m, __shfl_xor(m, 8));
    mx[r] = m;
  }
  #pragma unroll
  for (int r = 0; r < 4; r++){
    float s = 0.f;
    #pragma unroll
    for (int t = 0; t < 20; t++){
      float p = __expf(0.125f * (sacc[t][r] - mx[r]));
      sacc[t][r] = p;
      s += p;
    }
    s += __shfl_xor(s, 1); s += __shfl_xor(s, 2);
    s += __shfl_xor(s, 4); s += __shfl_xor(s, 8);
    inv_l[r] = 1.0f / s;
  }

  floatx4 oacc[4];
  #pragma unroll
  for (int dt = 0; dt < 4; dt++) oacc[dt] = (floatx4){0.f,0.f,0.f,0.f};
  for (int ch = 0; ch < 5; ++ch){
    const u16* src = (ch < 4)
        ? (kvx + ((size_t)(bt * 256 + ch * 64 + sj)) * 1024 + 512 + hh * 64 + sc)
        : (qc  + ((size_t)(tt * 64 + sj)) * 1536 + 1024 + hh * 64 + sc);
    u16x8 v0 = *(const u16x8*)(src);
    u16x8 v1 = *(const u16x8*)(src + 8);
    __syncthreads();
    #pragma unroll
    for (int e = 0; e < 8; e++) Vs[sc + e][sj]     = v0[e];
    #pragma unroll
    for (int e = 0; e < 8; e++) Vs[sc + 8 + e][sj] = v1[e];
    #pragma unroll
    for (int jt = 0; jt < 4; jt++){
      #pragma unroll
      for (int r = 0; r < 4; r++)
        Ps[i0 + 4*lg + r][jt*16 + l15] = f2b(sacc[ch*4+jt][r]);
    }
    __syncthreads();
    #pragma unroll
    for (int kk = 0; kk < 2; kk++){
      bhalf8 pf = *(const bhalf8*)(&Ps[i0 + l15][kk*32 + lg*8]);
      #pragma unroll
      for (int dt = 0; dt < 4; dt++){
        bhalf8 vfr = *(const bhalf8*)(&Vs[dt*16 + l15][kk*32 + lg*8]);
        oacc[dt] = __builtin_amdgcn_mfma_f32_16x16x32_bf16(pf, vfr, oacc[dt], 0,0,0);
      }
    }
  }

  // ---- vectorized epilogue via Ks scratch (dead after pass 1) ----
  #pragma unroll
  for (int dt = 0; dt < 4; dt++)
    #pragma unroll
    for (int r = 0; r < 4; r++)
      Ks[i0 + 4*lg + r][dt*16 + l15] = f2b(oacc[dt][r] * inv_l[r]);
  const int lr = ln >> 3, lcb = (ln & 7) * 8;
  #pragma unroll
  for (int p = 0; p < 2; p++){
    const int row = i0 + p * 8 + lr;
    u16x8 v = *(const u16x8*)(&Ks[row][lcb]);
    *(u16x8*)(o + ((size_t)(bt * 64 + row)) * 512 + hh * 64 + lcb) = v;
  }
}

// ---- MFMA self-attention: HEAD-MAJOR blocks (blk = h*128 + bt), T1 locality ----
__global__ __launch_bounds__(256) void sattn_k(
    const u16* __restrict__ qkv, u16* __restrict__ o2)
{
  __shared__ __align__(16) u16 Ks[64][72];
  __shared__ __align__(16) u16 Vs[64][72];
  __shared__ __align__(16) u16 Ps[64][72];
  const int blk = blockIdx.x;            // h*128 + bt  (head-major)
  const int hh = blk >> 7, bt = blk & 127;
  const int tid = threadIdx.x;
  const int wv = tid >> 6, ln = tid & 63;
  const int l15 = ln & 15, lg = ln >> 4;
  const int i0 = wv * 16;
  const int sj = tid >> 2, sc = (tid & 3) * 16;

  const u16* kp = qkv + ((size_t)sj * 128 + bt) * 2304 + 768 + hh * 64 + sc;
  u16x8 k0 = *(const u16x8*)(kp);
  u16x8 k1 = *(const u16x8*)(kp + 8);
  u16x8 v0 = *(const u16x8*)(kp + 768);
  u16x8 v1 = *(const u16x8*)(kp + 776);
  *(u16x8*)(&Ks[sj][sc])     = k0;
  *(u16x8*)(&Ks[sj][sc + 8]) = k1;
  #pragma unroll
  for (int e = 0; e < 8; e++) Vs[sc + e][sj]     = v0[e];
  #pragma unroll
  for (int e = 0; e < 8; e++) Vs[sc + 8 + e][sj] = v1[e];

  bhalf8 qf[2];
  {
    const u16* qp = qkv + ((size_t)(i0 + l15) * 128 + bt) * 2304 + hh * 64 + lg * 8;
    qf[0] = *(const bhalf8*)(qp);
    qf[1] = *(const bhalf8*)(qp + 32);
  }
  __syncthreads();

  floatx4 sacc[4];
  #pragma unroll
  for (int t = 0; t < 4; t++) sacc[t] = (floatx4){0.f,0.f,0.f,0.f};
  #pragma unroll
  for (int jt = 0; jt < 4; jt++){
    bhalf8 kf0 = *(const bhalf8*)(&Ks[jt*16 + l15][lg*8]);
    bhalf8 kf1 = *(const bhalf8*)(&Ks[jt*16 + l15][32 + lg*8]);
    sacc[jt] = __builtin_amdgcn_mfma_f32_16x16x32_bf16(qf[0], kf0, sacc[jt], 0,0,0);
    sacc[jt] = __builtin_amdgcn_mfma_f32_16x16x32_bf16(qf[1], kf1, sacc[jt], 0,0,0);
  }

  float inv_l[4];
  #pragma unroll
  for (int r = 0; r < 4; r++){
    float m = -1e30f;
    #pragma unroll
    for (int t = 0; t < 4; t++) m = fmaxf(m, sacc[t][r]);
    m = fmaxf(m, __shfl_xor(m, 1));
    m = fmaxf(m, __shfl_xor(m, 2));
    m = fmaxf(m, __shfl_xor(m, 4));
    m = fmaxf(m, __shfl_xor(m, 8));
    float s = 0.f;
    #pragma unroll
    for (int t = 0; t < 4; t++){
      float p = __expf(0.125f * (sacc[t][r] - m));
      sacc[t][r] = p;
      s += p;
    }
    s += __shfl_xor(s, 1); s += __shfl_xor(s, 2);
    s += __shfl_xor(s, 4); s += __shfl_xor(s, 8);
    inv_l[r] = 1.0f / s;
  }

  #pragma unroll
  for (int jt = 0; jt < 4; jt++){
    #pragma unroll
    for (int r = 0; r < 4; r++)
      Ps[i0 + 4*lg + r][jt*16 + l15] = f2b(sacc[jt][r]);
  }
  __syncthreads();

  floatx4 oacc[4];
  #pragma unroll
  for (int dt = 0; dt < 4; dt++) oacc[dt] = (floatx4){0.f,0.f,0.f,0.f};
  #pragma unroll
  for (int kk = 0; kk < 2; kk++){
    bhalf8 pf = *(const bhalf8*)(&Ps[i0 + l15][kk*32 + lg*8]);
    #pragma unroll
    for (int dt = 0; dt < 4; dt++){
      bhalf8 vfr = *(const bhalf8*)(&Vs[dt*16 + l15][kk*32 + lg*8]);
      oacc[dt] = __builtin_amdgcn_mfma_f32_16x16x32_bf16(pf, vfr, oacc[dt], 0,0,0);
    }
  }

  // ---- vectorized epilogue via Ks scratch (dead after QK^T) ----
  #pragma unroll
  for (int dt = 0; dt < 4; dt++)
    #pragma unroll
    for (int r = 0; r < 4; r++)
      Ks[i0 + 4*lg + r][dt*16 + l15] = f2b(oacc[dt][r] * inv_l[r]);
  const int lr = ln >> 3, lcb = (ln & 7) * 8;
  #pragma unroll
  for (int p = 0; p < 2; p++){
    const int row = i0 + p * 8 + lr;
    u16x8 v = *(const u16x8*)(&Ks[row][lcb]);
    *(u16x8*)(o2 + ((size_t)(row * 128 + bt)) * 768 + hh * 64 + lcb) = v;
  }
}

extern "C" void kernel_launch(void* const* d_in, const int* in_sizes, int n_in,
                              void* d_out, int out_size, void* d_ws, size_t ws_size,
                              hipStream_t stream)
{
  const float* vf   = (const float*)d_in[0];
  const float* lat  = (const float*)d_in[1];
  const float* nl0g = (const float*)d_in[2];
  const float* nl0b = (const float*)d_in[3];
  const float* pmg  = (const float*)d_in[4];
  const float* pmb  = (const float*)d_in[5];
  const float* plg  = (const float*)d_in[6];
  const float* plb  = (const float*)d_in[7];
  const float* Wq   = (const float*)d_in[8];
  const float* Wkv  = (const float*)d_in[9];
  const float* Wo   = (const float*)d_in[10];
  const float* ln1g = (const float*)d_in[11];
  const float* ln1b = (const float*)d_in[12];
  const float* Wqkv = (const float*)d_in[13];
  const float* bqkv = (const float*)d_in[14];
  const float* Wout = (const float*)d_in[15];
  const float* bout = (const float*)d_in[16];
  const float* ln2g = (const float*)d_in[17];
  const float* ln2b = (const float*)d_in[18];
  const float* Wfc  = (const float*)d_in[19];
  const float* bfc  = (const float*)d_in[20];
  const float* Wpr  = (const float*)d_in[21];
  const float* bpr  = (const float*)d_in[22];

  // ---- ws layout: base high-water 104,857,600 B; optional xm at 117.4M ----
  char* ws = (char*)d_ws;
  u16*    kvx    = (u16*)(ws + 0);          // 67,108,864 (dead after pattn)
  u16*    qkvb   = (u16*)(ws + 0);          // 37,748,736 (dead after sattn)
  u16*    o2b    = (u16*)(ws + 37748736);   // 12,582,912 (dead after Wout gemm)
  u16*    hb     = (u16*)(ws + 0);          // 50,331,648
  u16*    WoT    = (u16*)(ws + 50331648);
  u16*    WqkvT  = (u16*)(ws + 51118080);
  u16*    WoutT  = (u16*)(ws + 54657024);
  u16*    WfcT   = (u16*)(ws + 55836672);
  u16*    WprT   = (u16*)(ws + 60555264);   // ends 65,273,856
  u16*    WqT    = (u16*)(ws + 67108864);   // [512][768] then WkvT contiguous
  u16*    WkvT   = (u16*)(ws + 67895296);   // ends 69,468,160
  float*  yb     = (float*)(ws + 67108864); // written after WqT/WkvT dead
  u16*    llb    = (u16*)(ws + 92274688);
  u16*    qkv512 = (u16*)(ws + 93323264);   // [512][1536] bf16 (q|K|V)
  u16*    ob     = (u16*)(ws + 95420416);   // ends 103,809,024
  u16*    zb     = (u16*)(ws + 92274688);   // overlays llb..ob when dead
  u16*    xm     = (u16*)(ws + 117440512);  // 50,331,648, ends 167,772,160
  float2* stx    = (float2*)(ws + 93061120);
  const bool use_xm = (ws_size >= 167772160ull);

  const float* nof = nullptr;
  const float2* nos = nullptr;

  // early transposes: Wq (384 blks) + Wkv (768 blks) in ONE launch
  hipLaunchKernelGGL(transpB_k, dim3(1152), dim3(256), 0, stream,
                     Wq,  WqT,  768, 512,  384,
                     Wkv, WkvT, 768, 1024, 1152,
                     Wkv, WkvT, 768, 1024, 1152,
                     Wkv, WkvT, 768, 1024, 1152,
                     Wkv, WkvT, 768, 1024, 1152);
  hipLaunchKernelGGL(ln_lat2_k, dim3(512), dim3(256), 0, stream,
                     lat, llb, nl0g, nl0b, plg, plb);
  // q|kv_ll = ll @ [Wq|Wkv]: grid 4x6 = 24 blocks
  hipLaunchKernelGGL(mgemmW_k, dim3(24), dim3(512), 0, stream,
                     llb, WqT, (void*)qkv512, 512, 1536, 768, nof, 0, nof, 0, 1);
  if (use_xm){
    hipLaunchKernelGGL(ln_x_k, dim3(8192), dim3(256), 0, stream, vf, xm, pmg, pmb);
    // kv_x: 256x4 = 1024 blocks
    hipLaunchKernelGGL(mgemmW_k, dim3(1024), dim3(512), 0, stream,
                       xm, WkvT, (void*)kvx, 32768, 1024, 768, nof, 0, nof, 0, 1);
  } else {
    hipLaunchKernelGGL(stats_x_k, dim3(32768), dim3(256), 0, stream, vf, stx);
    hipLaunchKernelGGL(mgemm_k<1>, dim3(2048), dim3(256), 0, stream,
                       (const void*)vf, WkvT, (void*)kvx, 32768, 1024, 768,
                       nof, 0, nof, 0, 1, stx, pmg, pmb);
  }
  hipLaunchKernelGGL(pattn_k, dim3(1024), dim3(256), 0, stream, qkv512, kvx, ob);
  // late transposes in ONE launch
  hipLaunchKernelGGL(transpB_k, dim3(7296), dim3(256), 0, stream,
                     Wo,   WoT,   512,  768,  384,
                     Wqkv, WqkvT, 768,  2304, 2112,
                     Wout, WoutT, 768,  768,  2688,
                     Wfc,  WfcT,  768,  3072, 4992,
                     Wpr,  WprT,  3072, 768,  7296);
  // y = rearrange(ob @ Wo): 192 blocks (f32 out, rowperm)
  hipLaunchKernelGGL(mgemmW_k, dim3(192), dim3(512), 0, stream,
                     ob, WoT, (void*)yb, 8192, 768, 512, nof, 0, nof, 1, 0);
  hipLaunchKernelGGL(ln_f32_k, dim3(2048), dim3(256), 0, stream, yb, zb, ln1g, ln1b);
  // qkv: 576 blocks
  hipLaunchKernelGGL(mgemmW_k, dim3(576), dim3(512), 0, stream,
                     zb, WqkvT, (void*)qkvb, 8192, 2304, 768, bqkv, 0, nof, 0, 1);
  hipLaunchKernelGGL(sattn_k, dim3(1536), dim3(256), 0, stream, qkvb, o2b);
  // y += o2 @ Wout: 192 (f32 out, addsrc)
  hipLaunchKernelGGL(mgemmW_k, dim3(192), dim3(512), 0, stream,
                     o2b, WoutT, (void*)yb, 8192, 768, 768, bout, 0, yb, 0, 0);
  hipLaunchKernelGGL(ln_f32_k, dim3(2048), dim3(256), 0, stream, yb, zb, ln2g, ln2b);
  // h = QuickGELU(z2 @ fc): 768 blocks
  hipLaunchKernelGGL(mgemmW_k, dim3(768), dim3(512), 0, stream,
                     zb, WfcT, (void*)hb, 8192, 3072, 768, bfc, 1, nof, 0, 1);
  // out = y + h @ proj: 192 (K=3072, f32 out, addsrc)
  hipLaunchKernelGGL(mgemmW_k, dim3(192), dim3(512), 0, stream,
                     hb, WprT, d_out, 8192, 768, 3072, bpr, 0, yb, 0, 0);
}